// Round 5
// baseline (258.360 us; speedup 1.0000x reference)
//
#include <hip/hip_runtime.h>
#include <math.h>

#define LEN_Q 13294
#define LEN_IN 13294
#define NFRAMES 2
#define MTOT (LEN_Q * NFRAMES)   // 26588
#define HEADS 8
#define LEVELS 4
#define POINTS 4

typedef __attribute__((ext_vector_type(8))) short short8;
typedef __attribute__((ext_vector_type(4))) float f32x4;
typedef __attribute__((ext_vector_type(2))) unsigned int uint2v;
typedef __attribute__((ext_vector_type(4))) unsigned int uint4v;

__device__ __forceinline__ unsigned short f2bf(float x) {
    unsigned u = __builtin_bit_cast(unsigned, x);
    unsigned r = (u + 0x7fffu + ((u >> 16) & 1u)) >> 16;
    return (unsigned short)r;
}
__device__ __forceinline__ float bf2f(unsigned short b) {
    return __builtin_bit_cast(float, (unsigned)b << 16);
}
__device__ __forceinline__ float bfl(unsigned u) {
    return __builtin_bit_cast(float, u << 16);
}
__device__ __forceinline__ float bfh(unsigned u) {
    return __builtin_bit_cast(float, u & 0xffff0000u);
}
__device__ __forceinline__ short8 pack8(f32x4 x0, f32x4 x1) {
    short8 p;
    p[0]=(short)f2bf(x0.x); p[1]=(short)f2bf(x0.y); p[2]=(short)f2bf(x0.z); p[3]=(short)f2bf(x0.w);
    p[4]=(short)f2bf(x1.x); p[5]=(short)f2bf(x1.y); p[6]=(short)f2bf(x1.z); p[7]=(short)f2bf(x1.w);
    return p;
}

#define ASTR 264   // LDS row stride (shorts): 132 words/row -> even bank spread

// ---------------------------------------------------------------------------
// prep: all 4 weight transposes f32[K,N] -> bf16[N,K] in one dispatch.
// ---------------------------------------------------------------------------
__global__ __launch_bounds__(256) void prep_weights(
    const float* __restrict__ Wv,  const float* __restrict__ Woff,
    const float* __restrict__ Wat, const float* __restrict__ Wout,
    unsigned short* __restrict__ wvT,   // 256x256
    unsigned short* __restrict__ woaT,  // 384x256
    unsigned short* __restrict__ woutT) // 256x256
{
    const int b = blockIdx.x;
    const int k = threadIdx.x;
    const float* src; unsigned short* dst; int N; int n;
    if (b < 256)      { src = Wv;   dst = wvT;          N = 256; n = b; }
    else if (b < 512) { src = Woff; dst = woaT;         N = 256; n = b - 256; }
    else if (b < 640) { src = Wat;  dst = woaT + 65536; N = 128; n = b - 512; }
    else              { src = Wout; dst = woutT;        N = 256; n = b - 640; }
    dst[(size_t)n * 256 + k] = f2bf(src[(size_t)k * N + n]);
}

// ---------------------------------------------------------------------------
// gemm_fused2: one block per 64 rows computes ALL 640 output cols.
//   - Aval+Aq rows staged to LDS ONCE (bf16, 67.6 KB) -> A read once from HBM
//   - B fragments read directly from global (BT row-major: 16B contiguous,
//     L2-resident) -> K-loop has ZERO barriers and no global A traffic.
//   - val cols -> pair-duplicated head-major vdup table (sampler format).
// ---------------------------------------------------------------------------
__global__ __launch_bounds__(256, 2) void gemm_fused2(
    const float* __restrict__ Aval,
    const float* __restrict__ Aq,
    const unsigned short* __restrict__ BTv,   // [256,256]
    const unsigned short* __restrict__ BToa,  // [384,256]
    const float* __restrict__ bv,
    const float* __restrict__ boff,
    const float* __restrict__ battn,
    unsigned short* __restrict__ vdup,
    unsigned short* __restrict__ off16,
    unsigned short* __restrict__ at16,
    int M)
{
    __shared__ unsigned short Asv[64 * ASTR];
    __shared__ unsigned short Asq[64 * ASTR];

    const int t = threadIdx.x;
    const int w = t >> 6;
    const int L = t & 63;
    const int m0 = blockIdx.x * 64;

    // ---- stage both A tiles (f32 -> bf16), 64 f32 per thread per matrix ----
    {
        const int r = t >> 2;
        const int c0 = (t & 3) * 64;
        int arow = m0 + r; if (arow > M - 1) arow = M - 1;
        const float* pv = Aval + (size_t)arow * 256 + c0;
        const float* pq = Aq   + (size_t)arow * 256 + c0;
        unsigned short* dv = &Asv[r * ASTR + c0];
        unsigned short* dq = &Asq[r * ASTR + c0];
        #pragma unroll
        for (int cc = 0; cc < 64; cc += 16) {
            f32x4 v0 = *(const f32x4*)(pv + cc);
            f32x4 v1 = *(const f32x4*)(pv + cc + 4);
            f32x4 v2 = *(const f32x4*)(pv + cc + 8);
            f32x4 v3 = *(const f32x4*)(pv + cc + 12);
            f32x4 q0 = *(const f32x4*)(pq + cc);
            f32x4 q1 = *(const f32x4*)(pq + cc + 4);
            f32x4 q2 = *(const f32x4*)(pq + cc + 8);
            f32x4 q3 = *(const f32x4*)(pq + cc + 12);
            *(short8*)(dv + cc)     = pack8(v0, v1);
            *(short8*)(dv + cc + 8) = pack8(v2, v3);
            *(short8*)(dq + cc)     = pack8(q0, q1);
            *(short8*)(dq + cc + 8) = pack8(q2, q3);
        }
    }
    __syncthreads();

    const int mq = (w & 1) * 32;
    const int nq = (w >> 1) * 64;
    const int lr = L & 15;
    const int kq = (L >> 4) * 8;
    const int rr = (L >> 4) * 4;

    for (int nt = 0; nt < 5; ++nt) {
        const unsigned short* As = (nt < 2) ? Asv : Asq;
        const unsigned short* BTb = (nt < 2) ? (BTv + (size_t)nt * 128 * 256)
                                             : (BToa + (size_t)(nt - 2) * 128 * 256);
        f32x4 acc[2][4];
        #pragma unroll
        for (int i = 0; i < 2; ++i)
            #pragma unroll
            for (int j = 0; j < 4; ++j) acc[i][j] = (f32x4){0.f, 0.f, 0.f, 0.f};

        #pragma unroll
        for (int k0 = 0; k0 < 256; k0 += 32) {
            short8 af[2], bf[4];
            #pragma unroll
            for (int i = 0; i < 2; ++i)
                af[i] = *(const short8*)&As[(mq + i * 16 + lr) * ASTR + k0 + kq];
            #pragma unroll
            for (int j = 0; j < 4; ++j)
                bf[j] = *(const short8*)&BTb[(size_t)(nq + j * 16 + lr) * 256 + k0 + kq];
            #pragma unroll
            for (int i = 0; i < 2; ++i)
                #pragma unroll
                for (int j = 0; j < 4; ++j)
                    acc[i][j] = __builtin_amdgcn_mfma_f32_16x16x32_bf16(af[i], bf[j], acc[i][j], 0, 0, 0);
        }

        #pragma unroll
        for (int i = 0; i < 2; ++i) {
            #pragma unroll
            for (int r = 0; r < 4; ++r) {
                int m = m0 + mq + i * 16 + rr + r;
                if (m < M) {
                    #pragma unroll
                    for (int j = 0; j < 4; ++j) {
                        int colg = nt * 128 + nq + j * 16 + lr;
                        float vacc = acc[i][j][r];
                        if (colg < 256) {                    // value path -> vdup
                            int hh = colg >> 5, d = colg & 31;
                            int fr = (m >= LEN_Q) ? 1 : 0;
                            int e = m - fr * LEN_Q;
                            size_t ebase = ((size_t)(fr * 8 + hh) * (LEN_IN + 1) + e) * 64;
                            unsigned short bvv = f2bf(vacc + bv[colg]);
                            vdup[ebase + d] = bvv;                       // lo half of entry e
                            if (e > 0) vdup[ebase - 64 + 32 + d] = bvv;  // hi half of entry e-1
                        } else {
                            int oa = colg - 256;
                            if (oa < 256) off16[(size_t)m * 256 + oa] = f2bf(vacc + boff[oa]);
                            else          at16[(size_t)m * 128 + (oa - 256)] = f2bf(vacc + battn[oa - 256]);
                        }
                    }
                }
            }
        }
    }
}

// ---------------------------------------------------------------------------
// gemm_out2: same template (A bf16 staged once, B direct from global,
// barrier-free K-loop), 64 rows x 256 cols per block.
// ---------------------------------------------------------------------------
__global__ __launch_bounds__(256, 4) void gemm_out2(
    const unsigned short* __restrict__ A,
    const unsigned short* __restrict__ BT,
    const float* __restrict__ bias,
    float* __restrict__ C,
    int M)
{
    __shared__ unsigned short As[64 * ASTR];

    const int t = threadIdx.x;
    const int w = t >> 6;
    const int L = t & 63;
    const int m0 = blockIdx.x * 64;

    {
        const int r = t >> 2;
        const int c0 = (t & 3) * 64;
        int arow = m0 + r; if (arow > M - 1) arow = M - 1;
        const unsigned short* pa = A + (size_t)arow * 256 + c0;
        unsigned short* da = &As[r * ASTR + c0];
        #pragma unroll
        for (int cc = 0; cc < 64; cc += 8)
            *(short8*)(da + cc) = *(const short8*)(pa + cc);
    }
    __syncthreads();

    const int mq = (w & 1) * 32;
    const int nq = (w >> 1) * 64;
    const int lr = L & 15;
    const int kq = (L >> 4) * 8;
    const int rr = (L >> 4) * 4;

    for (int nt = 0; nt < 2; ++nt) {
        const unsigned short* BTb = BT + (size_t)nt * 128 * 256;
        f32x4 acc[2][4];
        #pragma unroll
        for (int i = 0; i < 2; ++i)
            #pragma unroll
            for (int j = 0; j < 4; ++j) acc[i][j] = (f32x4){0.f, 0.f, 0.f, 0.f};

        #pragma unroll
        for (int k0 = 0; k0 < 256; k0 += 32) {
            short8 af[2], bf[4];
            #pragma unroll
            for (int i = 0; i < 2; ++i)
                af[i] = *(const short8*)&As[(mq + i * 16 + lr) * ASTR + k0 + kq];
            #pragma unroll
            for (int j = 0; j < 4; ++j)
                bf[j] = *(const short8*)&BTb[(size_t)(nq + j * 16 + lr) * 256 + k0 + kq];
            #pragma unroll
            for (int i = 0; i < 2; ++i)
                #pragma unroll
                for (int j = 0; j < 4; ++j)
                    acc[i][j] = __builtin_amdgcn_mfma_f32_16x16x32_bf16(af[i], bf[j], acc[i][j], 0, 0, 0);
        }

        #pragma unroll
        for (int i = 0; i < 2; ++i) {
            #pragma unroll
            for (int r = 0; r < 4; ++r) {
                int m = m0 + mq + i * 16 + rr + r;
                if (m < M) {
                    #pragma unroll
                    for (int j = 0; j < 4; ++j) {
                        int n = nt * 128 + nq + j * 16 + lr;
                        C[(size_t)m * 256 + n] = acc[i][j][r] + bias[n];
                    }
                }
            }
        }
    }
}

// ---------------------------------------------------------------------------
// Sampler v10: full-line gathers via the pair-duplicated head-major table.
// (unchanged from round 4 — it moved the sampler off the critical path)
// ---------------------------------------------------------------------------
__global__ __launch_bounds__(256) void sample10(
    const unsigned short* __restrict__ vdup,   // bf16 [16][LEN_IN+1][64]
    const unsigned short* __restrict__ off,    // bf16 [MTOT,256]
    const unsigned short* __restrict__ attn,   // bf16 [MTOT,128]
    const float* __restrict__ refpts,          // [LEN_Q, LEVELS, 2]
    const int*   __restrict__ spatial,         // [LEVELS,2] (H,W)
    const int*   __restrict__ lsi,             // [LEVELS]
    unsigned short* __restrict__ samp)         // bf16 [MTOT,256]
{
    const int b = blockIdx.x;
    const int h = b & 7;            // head -> XCD (round-robin)
    const int chunk = b >> 3;       // 0..830
    const int t = threadIdx.x;
    const int rl = t >> 3;          // local row 0..31
    const int j = t & 7;            // lane within row

    int row = chunk * 32 + rl;
    const bool valid = row < MTOT;
    if (row > MTOT - 1) row = MTOT - 1;
    const int frame = row >= LEN_Q ? 1 : 0;
    const int q = row - frame * LEN_Q;

    __shared__ float w_s[32][68];   // 4 slot-weights per lp (padded stride)
    __shared__ int   b_s[32][20];   // pair-base byte offset per lp

    uint2v ov = *(const uint2v*)(off + (size_t)row * 256 + h * 32 + j * 4);
    unsigned av = *(const unsigned*)(attn + (size_t)row * 128 + h * 16 + j * 2);
    float t0 = bf2f((unsigned short)(av & 0xffffu));
    float t1 = bf2f((unsigned short)(av >> 16));

    float m = fmaxf(t0, t1);
    #pragma unroll
    for (int d = 1; d < 8; d <<= 1) m = fmaxf(m, __shfl_xor(m, d));
    float e0 = __expf(t0 - m);
    float e1 = __expf(t1 - m);
    float s = e0 + e1;
    #pragma unroll
    for (int d = 1; d < 8; d <<= 1) s += __shfl_xor(s, d);
    float inv = 1.f / s;
    float wt01[2] = { e0 * inv, e1 * inv };

    {
        const int l = j >> 1;
        const int Hl = spatial[l * 2], Wl = spatial[l * 2 + 1];
        const int start = lsi[l];
        const int slab = (frame * 8 + h) * (LEN_IN + 1);
        const float rx = refpts[((size_t)q * LEVELS + l) * 2];
        const float ry = refpts[((size_t)q * LEVELS + l) * 2 + 1];
        #pragma unroll
        for (int i = 0; i < 2; ++i) {
            const int lp = 2 * j + i;
            unsigned sel = (i == 0) ? ov.x : ov.y;
            float ox = bf2f((unsigned short)(sel & 0xffffu));
            float oy = bf2f((unsigned short)(sel >> 16));
            float locx = rx + ox * __builtin_amdgcn_rcpf((float)Wl);
            float locy = ry + oy * __builtin_amdgcn_rcpf((float)Hl);
            float wt = wt01[i];
            float x = locx * (float)Wl - 0.5f;
            float y = locy * (float)Hl - 0.5f;
            float x0f = floorf(x), y0f = floorf(y);
            float lx = x - x0f, ly = y - y0f;
            int x0 = (int)x0f, y0 = (int)y0f;
            int xbase = min(max(x0, 0), Wl - 2);
            int ybase = min(max(y0, 0), Hl - 2);
            float wxe0 = (x0 == xbase) ? (1.f - lx) : ((x0 == -1) ? lx : 0.f);
            float wxe1 = (x0 == xbase) ? lx : ((x0 == Wl - 1) ? (1.f - lx) : 0.f);
            float wye0 = (y0 == ybase) ? (1.f - ly) : ((y0 == -1) ? ly : 0.f);
            float wye1 = (y0 == ybase) ? ly : ((y0 == Hl - 1) ? (1.f - ly) : 0.f);
            b_s[rl][lp] = (slab + start + ybase * Wl + xbase) * 128;
            f32x4 wv;
            wv.x = wt * wxe0 * wye0;
            wv.y = wt * wxe1 * wye0;
            wv.z = wt * wxe0 * wye1;
            wv.w = wt * wxe1 * wye1;
            *(f32x4*)&w_s[rl][lp * 4] = wv;
        }
    }
    __syncthreads();

    const char* vb = (const char*)vdup;
    const unsigned lane16 = (unsigned)(j * 16);
    const int hi = (j >> 2) & 1;
    int ystr[4];
    #pragma unroll
    for (int l2 = 0; l2 < 4; ++l2) ystr[l2] = spatial[l2 * 2 + 1] * 128;

    f32x4  wreg[2][2];
    uint4v vbuf[2][4];
    auto fetch = [&](int buf, int g) {
        wreg[buf][0] = *(const f32x4*)&w_s[rl][(2 * g) * 4];
        wreg[buf][1] = *(const f32x4*)&w_s[rl][(2 * g + 1) * 4];
        int b0 = b_s[rl][2 * g];
        int b1 = b_s[rl][2 * g + 1];
        int ys = ystr[g >> 1];
        vbuf[buf][0] = *(const uint4v*)(vb + (unsigned)b0 + lane16);
        vbuf[buf][1] = *(const uint4v*)(vb + (unsigned)(b0 + ys) + lane16);
        vbuf[buf][2] = *(const uint4v*)(vb + (unsigned)b1 + lane16);
        vbuf[buf][3] = *(const uint4v*)(vb + (unsigned)(b1 + ys) + lane16);
    };

    float a[8];
    #pragma unroll
    for (int k = 0; k < 8; ++k) a[k] = 0.f;

    fetch(0, 0);
    #pragma unroll
    for (int g = 0; g < 8; ++g) {
        const int cur = g & 1;
        if (g < 7) fetch(cur ^ 1, g + 1);
        #pragma unroll
        for (int p = 0; p < 2; ++p) {
            f32x4 w4 = wreg[cur][p];
            float wy0 = hi ? w4.y : w4.x;
            float wy1 = hi ? w4.w : w4.z;
            uint4v v0 = vbuf[cur][p * 2];
            uint4v v1 = vbuf[cur][p * 2 + 1];
            #pragma unroll
            for (int k = 0; k < 4; ++k) {
                unsigned u0 = v0[k], u1 = v1[k];
                a[2 * k]     = fmaf(wy0, bfl(u0), a[2 * k]);
                a[2 * k + 1] = fmaf(wy0, bfh(u0), a[2 * k + 1]);
                a[2 * k]     = fmaf(wy1, bfl(u1), a[2 * k]);
                a[2 * k + 1] = fmaf(wy1, bfh(u1), a[2 * k + 1]);
            }
        }
    }

    #pragma unroll
    for (int k = 0; k < 8; ++k) a[k] += __shfl_xor(a[k], 4);

    if (valid && hi == 0) {
        uint4v o;
        #pragma unroll
        for (int k = 0; k < 4; ++k)
            o[k] = (unsigned)f2bf(a[2 * k]) | ((unsigned)f2bf(a[2 * k + 1]) << 16);
        *(uint4v*)(samp + (size_t)row * 256 + h * 32 + (j & 3) * 8) = o;
    }
}

// ---------------------------------------------------------------------------
extern "C" void kernel_launch(void* const* d_in, const int* in_sizes, int n_in,
                              void* d_out, int out_size, void* d_ws, size_t ws_size,
                              hipStream_t stream)
{
    const float* query   = (const float*)d_in[0];
    const float* refpts  = (const float*)d_in[1];
    const float* inflat  = (const float*)d_in[2];
    const int*   spatial = (const int*)d_in[3];
    const int*   lsi     = (const int*)d_in[4];
    const float* Wv      = (const float*)d_in[5];
    const float* bv      = (const float*)d_in[6];
    const float* Woff    = (const float*)d_in[7];
    const float* boff    = (const float*)d_in[8];
    const float* Wattn   = (const float*)d_in[9];
    const float* battn   = (const float*)d_in[10];
    const float* Wout    = (const float*)d_in[11];
    const float* bout    = (const float*)d_in[12];

    unsigned short* ws = (unsigned short*)d_ws;
    const size_t MR = (size_t)MTOT * 256;
    const size_t VDUP = (size_t)16 * (LEN_IN + 1) * 64;  // 13,614,080 shorts
    unsigned short* vdup   = ws;
    unsigned short* off16  = vdup + VDUP;               // MTOT*256
    unsigned short* at16   = off16 + MR;                // MTOT*128
    unsigned short* samp16 = at16 + (size_t)MTOT * 128; // MTOT*256
    unsigned short* wvT    = samp16 + MR;               // 256*256
    unsigned short* woaT   = wvT + 65536;               // 384*256
    unsigned short* woutT  = woaT + 98304;              // 256*256

    dim3 blk256(256);
    const int mBlocks64 = (MTOT + 63) / 64;             // 416

    hipLaunchKernelGGL(prep_weights, dim3(896), blk256, 0, stream,
                       Wv, Woff, Wattn, Wout, wvT, woaT, woutT);

    hipLaunchKernelGGL(gemm_fused2, dim3(mBlocks64), blk256, 0, stream,
                       inflat, query, wvT, woaT, bv, boff, battn,
                       vdup, off16, at16, MTOT);

    // 831 chunks of 32 rows per head, 8 heads -> 6648 blocks
    hipLaunchKernelGGL(sample10, dim3(6648), blk256, 0, stream,
                       vdup, off16, at16, refpts, spatial, lsi, samp16);

    hipLaunchKernelGGL(gemm_out2, dim3(mBlocks64), blk256, 0, stream,
                       samp16, woutT, bout, (float*)d_out, MTOT);
}

// Round 6
// 216.386 us; speedup vs baseline: 1.1940x; 1.1940x over previous
//
#include <hip/hip_runtime.h>
#include <math.h>

#define LEN_Q 13294
#define LEN_IN 13294
#define NFRAMES 2
#define MTOT (LEN_Q * NFRAMES)   // 26588
#define HEADS 8
#define LEVELS 4
#define POINTS 4

typedef __attribute__((ext_vector_type(8))) short short8;
typedef __attribute__((ext_vector_type(4))) float f32x4;
typedef __attribute__((ext_vector_type(2))) unsigned int uint2v;
typedef __attribute__((ext_vector_type(4))) unsigned int uint4v;

__device__ __forceinline__ unsigned short f2bf(float x) {
    unsigned u = __builtin_bit_cast(unsigned, x);
    unsigned r = (u + 0x7fffu + ((u >> 16) & 1u)) >> 16;
    return (unsigned short)r;
}
__device__ __forceinline__ float bf2f(unsigned short b) {
    return __builtin_bit_cast(float, (unsigned)b << 16);
}
__device__ __forceinline__ float bfl(unsigned u) {
    return __builtin_bit_cast(float, u << 16);
}
__device__ __forceinline__ float bfh(unsigned u) {
    return __builtin_bit_cast(float, u & 0xffff0000u);
}
__device__ __forceinline__ short8 pack8(f32x4 x0, f32x4 x1) {
    short8 p;
    p[0]=(short)f2bf(x0.x); p[1]=(short)f2bf(x0.y); p[2]=(short)f2bf(x0.z); p[3]=(short)f2bf(x0.w);
    p[4]=(short)f2bf(x1.x); p[5]=(short)f2bf(x1.y); p[6]=(short)f2bf(x1.z); p[7]=(short)f2bf(x1.w);
    return p;
}

// async global->LDS, 16B per lane. LDS dest must be wave-uniform base + lane*16.
__device__ __forceinline__ void gld_lds16(const unsigned short* g, unsigned short* l) {
    __builtin_amdgcn_global_load_lds(
        (const __attribute__((address_space(1))) void*)g,
        (__attribute__((address_space(3))) void*)l, 16, 0, 0);
}

// Stage a 128-row x 32-short tile (row stride 256 shorts in global) into linear
// LDS [128][32]. 256 threads x 2 loads. LDS byte dest = p*16 (p = load index)
// = wave_base + lane*16  -> satisfies the gload_lds dest constraint.
__device__ __forceinline__ void stage_tile(const unsigned short* __restrict__ g,
                                           unsigned short* lds, int t) {
    const unsigned short* ga = g + (t >> 2) * 256 + (t & 3) * 8;
    gld_lds16(ga, lds + t * 8);
    gld_lds16(ga + 64 * 256, lds + 2048 + t * 8);
}

// ---------------------------------------------------------------------------
// conv2bf: f32 -> bf16 for both A matrices (enables global_load_lds staging).
// ---------------------------------------------------------------------------
__global__ __launch_bounds__(256) void conv2bf(
    const float* __restrict__ a, const float* __restrict__ b,
    unsigned short* __restrict__ oa, unsigned short* __restrict__ ob)
{
    size_t gid = (size_t)blockIdx.x * 256 + threadIdx.x;
    size_t stride = (size_t)gridDim.x * 256;
    const size_t n8 = (size_t)MTOT * 256 / 8;
    for (size_t i = gid; i < n8; i += stride) {
        size_t off = i * 8;
        f32x4 x0 = *(const f32x4*)(a + off);
        f32x4 x1 = *(const f32x4*)(a + off + 4);
        *(short8*)(oa + off) = pack8(x0, x1);
        f32x4 y0 = *(const f32x4*)(b + off);
        f32x4 y1 = *(const f32x4*)(b + off + 4);
        *(short8*)(ob + off) = pack8(y0, y1);
    }
}

// ---------------------------------------------------------------------------
// prep: all 4 weight transposes f32[K,N] -> bf16[N,K] in one dispatch.
// ---------------------------------------------------------------------------
__global__ __launch_bounds__(256) void prep_weights(
    const float* __restrict__ Wv,  const float* __restrict__ Woff,
    const float* __restrict__ Wat, const float* __restrict__ Wout,
    unsigned short* __restrict__ wvT,   // 256x256
    unsigned short* __restrict__ woaT,  // 384x256
    unsigned short* __restrict__ woutT) // 256x256
{
    const int b = blockIdx.x;
    const int k = threadIdx.x;
    const float* src; unsigned short* dst; int N; int n;
    if (b < 256)      { src = Wv;   dst = wvT;          N = 256; n = b; }
    else if (b < 512) { src = Woff; dst = woaT;         N = 256; n = b - 256; }
    else if (b < 640) { src = Wat;  dst = woaT + 65536; N = 128; n = b - 512; }
    else              { src = Wout; dst = woutT;        N = 256; n = b - 640; }
    dst[(size_t)n * 256 + k] = f2bf(src[(size_t)k * N + n]);
}

// ---------------------------------------------------------------------------
// gemm_fused3: m97-style. 128x128 tile, BK=32, double-buffered LINEAR LDS
// staged entirely by global_load_lds width-16 (no VGPR round trip, no in-loop
// VALU pack), ONE barrier per k-step. Grid (5 n-tiles, 208 m-blocks).
// Epilogue identical to round-4 (vdup pair-dup head-major + off/at).
// ---------------------------------------------------------------------------
__global__ __launch_bounds__(256) void gemm_fused3(
    const unsigned short* __restrict__ A16v,  // bf16 [MTOT,256]
    const unsigned short* __restrict__ A16q,  // bf16 [MTOT,256]
    const unsigned short* __restrict__ BTv,   // [256,256]
    const unsigned short* __restrict__ BToa,  // [384,256]
    const float* __restrict__ bv,
    const float* __restrict__ boff,
    const float* __restrict__ battn,
    unsigned short* __restrict__ vdup,
    unsigned short* __restrict__ off16,
    unsigned short* __restrict__ at16,
    int M)
{
    __shared__ unsigned short As[2 * 4096];   // 2 x [128][32] linear
    __shared__ unsigned short Bs[2 * 4096];

    const int t = threadIdx.x;
    const int w = t >> 6;
    const int L = t & 63;
    const int nt = blockIdx.x;
    const int m0 = blockIdx.y * 128;

    const unsigned short* Abase = ((nt < 2) ? A16v : A16q) + (size_t)m0 * 256;
    const unsigned short* Bbase = (nt < 2) ? (BTv + (size_t)nt * 128 * 256)
                                           : (BToa + (size_t)(nt - 2) * 128 * 256);

    const int mq = (w & 1) * 64;
    const int nq = (w >> 1) * 64;
    const int lr = L & 15;
    const int kq = (L >> 4) * 8;

    f32x4 acc[4][4];
    #pragma unroll
    for (int i = 0; i < 4; ++i)
        #pragma unroll
        for (int j = 0; j < 4; ++j) acc[i][j] = (f32x4){0.f, 0.f, 0.f, 0.f};

    stage_tile(Abase, As, t);
    stage_tile(Bbase, Bs, t);

    #pragma unroll
    for (int ks = 0; ks < 8; ++ks) {
        const int cur = ks & 1;
        __syncthreads();                       // drains vmcnt -> buf[cur] ready
        if (ks < 7) {                          // prefetch next k-tile
            stage_tile(Abase + (ks + 1) * 32, As + (cur ^ 1) * 4096, t);
            stage_tile(Bbase + (ks + 1) * 32, Bs + (cur ^ 1) * 4096, t);
        }
        short8 af[4], bf[4];
        #pragma unroll
        for (int i = 0; i < 4; ++i)
            af[i] = *(const short8*)&As[cur * 4096 + (mq + i * 16 + lr) * 32 + kq];
        #pragma unroll
        for (int j = 0; j < 4; ++j)
            bf[j] = *(const short8*)&Bs[cur * 4096 + (nq + j * 16 + lr) * 32 + kq];
        #pragma unroll
        for (int i = 0; i < 4; ++i)
            #pragma unroll
            for (int j = 0; j < 4; ++j)
                acc[i][j] = __builtin_amdgcn_mfma_f32_16x16x32_bf16(af[i], bf[j], acc[i][j], 0, 0, 0);
    }

    const int rr = (L >> 4) * 4;
    #pragma unroll
    for (int i = 0; i < 4; ++i) {
        #pragma unroll
        for (int r = 0; r < 4; ++r) {
            int m = m0 + mq + i * 16 + rr + r;
            if (m < M) {
                #pragma unroll
                for (int j = 0; j < 4; ++j) {
                    int colg = nt * 128 + nq + j * 16 + lr;
                    float vacc = acc[i][j][r];
                    if (colg < 256) {                    // value path -> vdup
                        int hh = colg >> 5, d = colg & 31;
                        int fr = (m >= LEN_Q) ? 1 : 0;
                        int e = m - fr * LEN_Q;
                        size_t ebase = ((size_t)(fr * 8 + hh) * (LEN_IN + 1) + e) * 64;
                        unsigned short bvv = f2bf(vacc + bv[colg]);
                        vdup[ebase + d] = bvv;                       // lo half of entry e
                        if (e > 0) vdup[ebase - 64 + 32 + d] = bvv;  // hi half of entry e-1
                    } else {
                        int oa = colg - 256;
                        if (oa < 256) off16[(size_t)m * 256 + oa] = f2bf(vacc + boff[oa]);
                        else          at16[(size_t)m * 128 + (oa - 256)] = f2bf(vacc + battn[oa - 256]);
                    }
                }
            }
        }
    }
}

// ---------------------------------------------------------------------------
// gemm_out3: same m97-style template; A = samp16 (already bf16). Grid (2,208).
// ---------------------------------------------------------------------------
__global__ __launch_bounds__(256) void gemm_out3(
    const unsigned short* __restrict__ A,     // bf16 [MTOT,256]
    const unsigned short* __restrict__ BT,    // [256,256]
    const float* __restrict__ bias,
    float* __restrict__ C,
    int M)
{
    __shared__ unsigned short As[2 * 4096];
    __shared__ unsigned short Bs[2 * 4096];

    const int t = threadIdx.x;
    const int w = t >> 6;
    const int L = t & 63;
    const int n0 = blockIdx.x * 128;
    const int m0 = blockIdx.y * 128;

    const unsigned short* Abase = A + (size_t)m0 * 256;
    const unsigned short* Bbase = BT + (size_t)n0 * 256;

    const int mq = (w & 1) * 64;
    const int nq = (w >> 1) * 64;
    const int lr = L & 15;
    const int kq = (L >> 4) * 8;

    f32x4 acc[4][4];
    #pragma unroll
    for (int i = 0; i < 4; ++i)
        #pragma unroll
        for (int j = 0; j < 4; ++j) acc[i][j] = (f32x4){0.f, 0.f, 0.f, 0.f};

    stage_tile(Abase, As, t);
    stage_tile(Bbase, Bs, t);

    #pragma unroll
    for (int ks = 0; ks < 8; ++ks) {
        const int cur = ks & 1;
        __syncthreads();
        if (ks < 7) {
            stage_tile(Abase + (ks + 1) * 32, As + (cur ^ 1) * 4096, t);
            stage_tile(Bbase + (ks + 1) * 32, Bs + (cur ^ 1) * 4096, t);
        }
        short8 af[4], bf[4];
        #pragma unroll
        for (int i = 0; i < 4; ++i)
            af[i] = *(const short8*)&As[cur * 4096 + (mq + i * 16 + lr) * 32 + kq];
        #pragma unroll
        for (int j = 0; j < 4; ++j)
            bf[j] = *(const short8*)&Bs[cur * 4096 + (nq + j * 16 + lr) * 32 + kq];
        #pragma unroll
        for (int i = 0; i < 4; ++i)
            #pragma unroll
            for (int j = 0; j < 4; ++j)
                acc[i][j] = __builtin_amdgcn_mfma_f32_16x16x32_bf16(af[i], bf[j], acc[i][j], 0, 0, 0);
    }

    const int rr = (L >> 4) * 4;
    #pragma unroll
    for (int i = 0; i < 4; ++i) {
        #pragma unroll
        for (int r = 0; r < 4; ++r) {
            int m = m0 + mq + i * 16 + rr + r;
            if (m < M) {
                #pragma unroll
                for (int j = 0; j < 4; ++j) {
                    int n = n0 + nq + j * 16 + lr;
                    C[(size_t)m * 256 + n] = acc[i][j][r] + bias[n];
                }
            }
        }
    }
}

// ---------------------------------------------------------------------------
// Sampler v10 (unchanged): full-line gathers via pair-duplicated head-major
// vdup table; head-partitioned for XCD-L2 residency.
// ---------------------------------------------------------------------------
__global__ __launch_bounds__(256) void sample10(
    const unsigned short* __restrict__ vdup,   // bf16 [16][LEN_IN+1][64]
    const unsigned short* __restrict__ off,    // bf16 [MTOT,256]
    const unsigned short* __restrict__ attn,   // bf16 [MTOT,128]
    const float* __restrict__ refpts,          // [LEN_Q, LEVELS, 2]
    const int*   __restrict__ spatial,         // [LEVELS,2] (H,W)
    const int*   __restrict__ lsi,             // [LEVELS]
    unsigned short* __restrict__ samp)         // bf16 [MTOT,256]
{
    const int b = blockIdx.x;
    const int h = b & 7;            // head -> XCD (round-robin)
    const int chunk = b >> 3;       // 0..830
    const int t = threadIdx.x;
    const int rl = t >> 3;          // local row 0..31
    const int j = t & 7;            // lane within row

    int row = chunk * 32 + rl;
    const bool valid = row < MTOT;
    if (row > MTOT - 1) row = MTOT - 1;
    const int frame = row >= LEN_Q ? 1 : 0;
    const int q = row - frame * LEN_Q;

    __shared__ float w_s[32][68];   // 4 slot-weights per lp (padded stride)
    __shared__ int   b_s[32][20];   // pair-base byte offset per lp

    uint2v ov = *(const uint2v*)(off + (size_t)row * 256 + h * 32 + j * 4);
    unsigned av = *(const unsigned*)(attn + (size_t)row * 128 + h * 16 + j * 2);
    float t0 = bf2f((unsigned short)(av & 0xffffu));
    float t1 = bf2f((unsigned short)(av >> 16));

    float m = fmaxf(t0, t1);
    #pragma unroll
    for (int d = 1; d < 8; d <<= 1) m = fmaxf(m, __shfl_xor(m, d));
    float e0 = __expf(t0 - m);
    float e1 = __expf(t1 - m);
    float s = e0 + e1;
    #pragma unroll
    for (int d = 1; d < 8; d <<= 1) s += __shfl_xor(s, d);
    float inv = 1.f / s;
    float wt01[2] = { e0 * inv, e1 * inv };

    {
        const int l = j >> 1;
        const int Hl = spatial[l * 2], Wl = spatial[l * 2 + 1];
        const int start = lsi[l];
        const int slab = (frame * 8 + h) * (LEN_IN + 1);
        const float rx = refpts[((size_t)q * LEVELS + l) * 2];
        const float ry = refpts[((size_t)q * LEVELS + l) * 2 + 1];
        #pragma unroll
        for (int i = 0; i < 2; ++i) {
            const int lp = 2 * j + i;
            unsigned sel = (i == 0) ? ov.x : ov.y;
            float ox = bf2f((unsigned short)(sel & 0xffffu));
            float oy = bf2f((unsigned short)(sel >> 16));
            float locx = rx + ox * __builtin_amdgcn_rcpf((float)Wl);
            float locy = ry + oy * __builtin_amdgcn_rcpf((float)Hl);
            float wt = wt01[i];
            float x = locx * (float)Wl - 0.5f;
            float y = locy * (float)Hl - 0.5f;
            float x0f = floorf(x), y0f = floorf(y);
            float lx = x - x0f, ly = y - y0f;
            int x0 = (int)x0f, y0 = (int)y0f;
            int xbase = min(max(x0, 0), Wl - 2);
            int ybase = min(max(y0, 0), Hl - 2);
            float wxe0 = (x0 == xbase) ? (1.f - lx) : ((x0 == -1) ? lx : 0.f);
            float wxe1 = (x0 == xbase) ? lx : ((x0 == Wl - 1) ? (1.f - lx) : 0.f);
            float wye0 = (y0 == ybase) ? (1.f - ly) : ((y0 == -1) ? ly : 0.f);
            float wye1 = (y0 == ybase) ? ly : ((y0 == Hl - 1) ? (1.f - ly) : 0.f);
            b_s[rl][lp] = (slab + start + ybase * Wl + xbase) * 128;
            f32x4 wv;
            wv.x = wt * wxe0 * wye0;
            wv.y = wt * wxe1 * wye0;
            wv.z = wt * wxe0 * wye1;
            wv.w = wt * wxe1 * wye1;
            *(f32x4*)&w_s[rl][lp * 4] = wv;
        }
    }
    __syncthreads();

    const char* vb = (const char*)vdup;
    const unsigned lane16 = (unsigned)(j * 16);
    const int hi = (j >> 2) & 1;
    int ystr[4];
    #pragma unroll
    for (int l2 = 0; l2 < 4; ++l2) ystr[l2] = spatial[l2 * 2 + 1] * 128;

    f32x4  wreg[2][2];
    uint4v vbuf[2][4];
    auto fetch = [&](int buf, int g) {
        wreg[buf][0] = *(const f32x4*)&w_s[rl][(2 * g) * 4];
        wreg[buf][1] = *(const f32x4*)&w_s[rl][(2 * g + 1) * 4];
        int b0 = b_s[rl][2 * g];
        int b1 = b_s[rl][2 * g + 1];
        int ys = ystr[g >> 1];
        vbuf[buf][0] = *(const uint4v*)(vb + (unsigned)b0 + lane16);
        vbuf[buf][1] = *(const uint4v*)(vb + (unsigned)(b0 + ys) + lane16);
        vbuf[buf][2] = *(const uint4v*)(vb + (unsigned)b1 + lane16);
        vbuf[buf][3] = *(const uint4v*)(vb + (unsigned)(b1 + ys) + lane16);
    };

    float a[8];
    #pragma unroll
    for (int k = 0; k < 8; ++k) a[k] = 0.f;

    fetch(0, 0);
    #pragma unroll
    for (int g = 0; g < 8; ++g) {
        const int cur = g & 1;
        if (g < 7) fetch(cur ^ 1, g + 1);
        #pragma unroll
        for (int p = 0; p < 2; ++p) {
            f32x4 w4 = wreg[cur][p];
            float wy0 = hi ? w4.y : w4.x;
            float wy1 = hi ? w4.w : w4.z;
            uint4v v0 = vbuf[cur][p * 2];
            uint4v v1 = vbuf[cur][p * 2 + 1];
            #pragma unroll
            for (int k = 0; k < 4; ++k) {
                unsigned u0 = v0[k], u1 = v1[k];
                a[2 * k]     = fmaf(wy0, bfl(u0), a[2 * k]);
                a[2 * k + 1] = fmaf(wy0, bfh(u0), a[2 * k + 1]);
                a[2 * k]     = fmaf(wy1, bfl(u1), a[2 * k]);
                a[2 * k + 1] = fmaf(wy1, bfh(u1), a[2 * k + 1]);
            }
        }
    }

    #pragma unroll
    for (int k = 0; k < 8; ++k) a[k] += __shfl_xor(a[k], 4);

    if (valid && hi == 0) {
        uint4v o;
        #pragma unroll
        for (int k = 0; k < 4; ++k)
            o[k] = (unsigned)f2bf(a[2 * k]) | ((unsigned)f2bf(a[2 * k + 1]) << 16);
        *(uint4v*)(samp + (size_t)row * 256 + h * 32 + (j & 3) * 8) = o;
    }
}

// ---------------------------------------------------------------------------
extern "C" void kernel_launch(void* const* d_in, const int* in_sizes, int n_in,
                              void* d_out, int out_size, void* d_ws, size_t ws_size,
                              hipStream_t stream)
{
    const float* query   = (const float*)d_in[0];
    const float* refpts  = (const float*)d_in[1];
    const float* inflat  = (const float*)d_in[2];
    const int*   spatial = (const int*)d_in[3];
    const int*   lsi     = (const int*)d_in[4];
    const float* Wv      = (const float*)d_in[5];
    const float* bv      = (const float*)d_in[6];
    const float* Woff    = (const float*)d_in[7];
    const float* boff    = (const float*)d_in[8];
    const float* Wattn   = (const float*)d_in[9];
    const float* battn   = (const float*)d_in[10];
    const float* Wout    = (const float*)d_in[11];
    const float* bout    = (const float*)d_in[12];

    unsigned short* ws = (unsigned short*)d_ws;
    const size_t MR = (size_t)MTOT * 256;                // 6,806,528 shorts
    const size_t VDUP = (size_t)16 * (LEN_IN + 1) * 64;  // 13,614,080 shorts
    unsigned short* vdup   = ws;
    unsigned short* off16  = vdup + VDUP;                // MTOT*256
    unsigned short* at16   = off16 + MR;                 // MTOT*128
    unsigned short* samp16 = at16 + (size_t)MTOT * 128;  // MTOT*256
    unsigned short* a16v   = samp16 + MR;                // MTOT*256 (bf16 inflat)
    unsigned short* a16q   = a16v + MR;                  // MTOT*256 (bf16 query)
    unsigned short* wvT    = a16q + MR;                  // 256*256
    unsigned short* woaT   = wvT + 65536;                // 384*256
    unsigned short* woutT  = woaT + 98304;               // 256*256

    dim3 blk256(256);
    const int mBlocks = (MTOT + 127) / 128;              // 208

    hipLaunchKernelGGL(conv2bf, dim3(2048), blk256, 0, stream,
                       inflat, query, a16v, a16q);

    hipLaunchKernelGGL(prep_weights, dim3(896), blk256, 0, stream,
                       Wv, Woff, Wattn, Wout, wvT, woaT, woutT);

    hipLaunchKernelGGL(gemm_fused3, dim3(5, mBlocks), blk256, 0, stream,
                       a16v, a16q, wvT, woaT, bv, boff, battn,
                       vdup, off16, at16, MTOT);

    // 831 chunks of 32 rows per head, 8 heads -> 6648 blocks
    hipLaunchKernelGGL(sample10, dim3(6648), blk256, 0, stream,
                       vdup, off16, at16, refpts, spatial, lsi, samp16);

    hipLaunchKernelGGL(gemm_out3, dim3(2, mBlocks), blk256, 0, stream,
                       samp16, woutT, bout, (float*)d_out, MTOT);
}

// Round 7
// 209.168 us; speedup vs baseline: 1.2352x; 1.0345x over previous
//
#include <hip/hip_runtime.h>
#include <math.h>

#define LEN_Q 13294
#define LEN_IN 13294
#define NFRAMES 2
#define MTOT (LEN_Q * NFRAMES)   // 26588
#define HEADS 8
#define LEVELS 4
#define POINTS 4

typedef __attribute__((ext_vector_type(8))) short short8;
typedef __attribute__((ext_vector_type(4))) float f32x4;
typedef __attribute__((ext_vector_type(2))) unsigned int uint2v;
typedef __attribute__((ext_vector_type(4))) unsigned int uint4v;

__device__ __forceinline__ unsigned short f2bf(float x) {
    unsigned u = __builtin_bit_cast(unsigned, x);
    unsigned r = (u + 0x7fffu + ((u >> 16) & 1u)) >> 16;
    return (unsigned short)r;
}
__device__ __forceinline__ float bf2f(unsigned short b) {
    return __builtin_bit_cast(float, (unsigned)b << 16);
}
__device__ __forceinline__ float bfl(unsigned u) {
    return __builtin_bit_cast(float, u << 16);
}
__device__ __forceinline__ float bfh(unsigned u) {
    return __builtin_bit_cast(float, u & 0xffff0000u);
}
__device__ __forceinline__ short8 pack8(f32x4 x0, f32x4 x1) {
    short8 p;
    p[0]=(short)f2bf(x0.x); p[1]=(short)f2bf(x0.y); p[2]=(short)f2bf(x0.z); p[3]=(short)f2bf(x0.w);
    p[4]=(short)f2bf(x1.x); p[5]=(short)f2bf(x1.y); p[6]=(short)f2bf(x1.z); p[7]=(short)f2bf(x1.w);
    return p;
}

// async global->LDS, 16B per lane. LDS dest must be wave-uniform base + lane*16.
__device__ __forceinline__ void gld_lds16(const unsigned short* g, unsigned short* l) {
    __builtin_amdgcn_global_load_lds(
        (const __attribute__((address_space(1))) void*)g,
        (__attribute__((address_space(3))) void*)l, 16, 0, 0);
}

// Stage a 128-row x 32-short tile (row stride 256 shorts in global) into linear
// LDS [128][32]. 256 threads x 2 loads.
__device__ __forceinline__ void stage_tile(const unsigned short* __restrict__ g,
                                           unsigned short* lds, int t) {
    const unsigned short* ga = g + (t >> 2) * 256 + (t & 3) * 8;
    gld_lds16(ga, lds + t * 8);
    gld_lds16(ga + 64 * 256, lds + 2048 + t * 8);
}

// ---------------------------------------------------------------------------
// prep_all: weight transposes (blocks 0..895) + f32->bf16 conversion of both
// A matrices (blocks 896.., grid-stride) in ONE dispatch.
// ---------------------------------------------------------------------------
#define CONV_BLOCKS 2048
__global__ __launch_bounds__(256) void prep_all(
    const float* __restrict__ Wv,  const float* __restrict__ Woff,
    const float* __restrict__ Wat, const float* __restrict__ Wout,
    unsigned short* __restrict__ wvT,   // 256x256
    unsigned short* __restrict__ woaT,  // 384x256
    unsigned short* __restrict__ woutT, // 256x256
    const float* __restrict__ a, const float* __restrict__ b,
    unsigned short* __restrict__ oa, unsigned short* __restrict__ ob)
{
    const int blk = blockIdx.x;
    const int k = threadIdx.x;
    if (blk < 896) {
        const float* src; unsigned short* dst; int N; int n;
        if (blk < 256)      { src = Wv;   dst = wvT;          N = 256; n = blk; }
        else if (blk < 512) { src = Woff; dst = woaT;         N = 256; n = blk - 256; }
        else if (blk < 640) { src = Wat;  dst = woaT + 65536; N = 128; n = blk - 512; }
        else                { src = Wout; dst = woutT;        N = 256; n = blk - 640; }
        dst[(size_t)n * 256 + k] = f2bf(src[(size_t)k * N + n]);
        return;
    }
    size_t gid = (size_t)(blk - 896) * 256 + k;
    size_t stride = (size_t)CONV_BLOCKS * 256;
    const size_t n8 = (size_t)MTOT * 256 / 8;
    for (size_t i = gid; i < n8; i += stride) {
        size_t off = i * 8;
        f32x4 x0 = *(const f32x4*)(a + off);
        f32x4 x1 = *(const f32x4*)(a + off + 4);
        *(short8*)(oa + off) = pack8(x0, x1);
        f32x4 y0 = *(const f32x4*)(b + off);
        f32x4 y1 = *(const f32x4*)(b + off + 4);
        *(short8*)(ob + off) = pack8(y0, y1);
    }
}

// ---------------------------------------------------------------------------
// gemm_fused3: m97-style, 128x128 tile, BK=32, double-buffered linear LDS,
// global_load_lds width-16 staging, one barrier per k-step.
// XCD co-location swizzle: all 5 n-tiles of an m-tile share bid%8 (same XCD,
// adjacent k) -> A m-tile fetched ONCE per XCD L2 instead of 5x across XCDs.
// Grid: 1040 = 8 xcd * 26 m-groups * 5 nt.  (208 m-tiles = 26*8 exactly)
// ---------------------------------------------------------------------------
__global__ __launch_bounds__(256) void gemm_fused3(
    const unsigned short* __restrict__ A16v,  // bf16 [MTOT,256]
    const unsigned short* __restrict__ A16q,  // bf16 [MTOT,256]
    const unsigned short* __restrict__ BTv,   // [256,256]
    const unsigned short* __restrict__ BToa,  // [384,256]
    const float* __restrict__ bv,
    const float* __restrict__ boff,
    const float* __restrict__ battn,
    unsigned short* __restrict__ vdup,
    unsigned short* __restrict__ off16,
    unsigned short* __restrict__ at16,
    int M)
{
    __shared__ unsigned short As[2 * 4096];   // 2 x [128][32] linear
    __shared__ unsigned short Bs[2 * 4096];

    const int t = threadIdx.x;
    const int w = t >> 6;
    const int L = t & 63;

    const int bid = blockIdx.x;
    const int xcd = bid & 7;
    const int kk = bid >> 3;                  // 0..129
    const int nt = kk % 5;
    const int m0 = ((kk / 5) * 8 + xcd) * 128;

    const unsigned short* Abase = ((nt < 2) ? A16v : A16q) + (size_t)m0 * 256;
    const unsigned short* Bbase = (nt < 2) ? (BTv + (size_t)nt * 128 * 256)
                                           : (BToa + (size_t)(nt - 2) * 128 * 256);

    const int mq = (w & 1) * 64;
    const int nq = (w >> 1) * 64;
    const int lr = L & 15;
    const int kq = (L >> 4) * 8;

    f32x4 acc[4][4];
    #pragma unroll
    for (int i = 0; i < 4; ++i)
        #pragma unroll
        for (int j = 0; j < 4; ++j) acc[i][j] = (f32x4){0.f, 0.f, 0.f, 0.f};

    stage_tile(Abase, As, t);
    stage_tile(Bbase, Bs, t);

    #pragma unroll
    for (int ks = 0; ks < 8; ++ks) {
        const int cur = ks & 1;
        __syncthreads();                       // drains vmcnt -> buf[cur] ready
        if (ks < 7) {                          // prefetch next k-tile
            stage_tile(Abase + (ks + 1) * 32, As + (cur ^ 1) * 4096, t);
            stage_tile(Bbase + (ks + 1) * 32, Bs + (cur ^ 1) * 4096, t);
        }
        short8 af[4], bf[4];
        #pragma unroll
        for (int i = 0; i < 4; ++i)
            af[i] = *(const short8*)&As[cur * 4096 + (mq + i * 16 + lr) * 32 + kq];
        #pragma unroll
        for (int j = 0; j < 4; ++j)
            bf[j] = *(const short8*)&Bs[cur * 4096 + (nq + j * 16 + lr) * 32 + kq];
        #pragma unroll
        for (int i = 0; i < 4; ++i)
            #pragma unroll
            for (int j = 0; j < 4; ++j)
                acc[i][j] = __builtin_amdgcn_mfma_f32_16x16x32_bf16(af[i], bf[j], acc[i][j], 0, 0, 0);
    }

    const int rr = (L >> 4) * 4;
    #pragma unroll
    for (int i = 0; i < 4; ++i) {
        #pragma unroll
        for (int r = 0; r < 4; ++r) {
            int m = m0 + mq + i * 16 + rr + r;
            if (m < M) {
                #pragma unroll
                for (int j = 0; j < 4; ++j) {
                    int colg = nt * 128 + nq + j * 16 + lr;
                    float vacc = acc[i][j][r];
                    if (colg < 256) {                    // value path -> vdup
                        int hh = colg >> 5, d = colg & 31;
                        int fr = (m >= LEN_Q) ? 1 : 0;
                        int e = m - fr * LEN_Q;
                        size_t ebase = ((size_t)(fr * 8 + hh) * (LEN_IN + 1) + e) * 64;
                        unsigned short bvv = f2bf(vacc + bv[colg]);
                        vdup[ebase + d] = bvv;                       // lo half of entry e
                        if (e > 0) vdup[ebase - 64 + 32 + d] = bvv;  // hi half of entry e-1
                    } else {
                        int oa = colg - 256;
                        if (oa < 256) off16[(size_t)m * 256 + oa] = f2bf(vacc + boff[oa]);
                        else          at16[(size_t)m * 128 + (oa - 256)] = f2bf(vacc + battn[oa - 256]);
                    }
                }
            }
        }
    }
}

// ---------------------------------------------------------------------------
// gemm_out3: same template; A = samp16 (already bf16). XCD-swizzled grid:
// 416 = 8 xcd * 26 m-groups * 2 nt; both n-tiles of an m-tile on one XCD.
// ---------------------------------------------------------------------------
__global__ __launch_bounds__(256) void gemm_out3(
    const unsigned short* __restrict__ A,     // bf16 [MTOT,256]
    const unsigned short* __restrict__ BT,    // [256,256]
    const float* __restrict__ bias,
    float* __restrict__ C,
    int M)
{
    __shared__ unsigned short As[2 * 4096];
    __shared__ unsigned short Bs[2 * 4096];

    const int t = threadIdx.x;
    const int w = t >> 6;
    const int L = t & 63;

    const int bid = blockIdx.x;
    const int xcd = bid & 7;
    const int kk = bid >> 3;                  // 0..51
    const int nt = kk % 2;
    const int m0 = ((kk / 2) * 8 + xcd) * 128;
    const int n0 = nt * 128;

    const unsigned short* Abase = A + (size_t)m0 * 256;
    const unsigned short* Bbase = BT + (size_t)n0 * 256;

    const int mq = (w & 1) * 64;
    const int nq = (w >> 1) * 64;
    const int lr = L & 15;
    const int kq = (L >> 4) * 8;

    f32x4 acc[4][4];
    #pragma unroll
    for (int i = 0; i < 4; ++i)
        #pragma unroll
        for (int j = 0; j < 4; ++j) acc[i][j] = (f32x4){0.f, 0.f, 0.f, 0.f};

    stage_tile(Abase, As, t);
    stage_tile(Bbase, Bs, t);

    #pragma unroll
    for (int ks = 0; ks < 8; ++ks) {
        const int cur = ks & 1;
        __syncthreads();
        if (ks < 7) {
            stage_tile(Abase + (ks + 1) * 32, As + (cur ^ 1) * 4096, t);
            stage_tile(Bbase + (ks + 1) * 32, Bs + (cur ^ 1) * 4096, t);
        }
        short8 af[4], bf[4];
        #pragma unroll
        for (int i = 0; i < 4; ++i)
            af[i] = *(const short8*)&As[cur * 4096 + (mq + i * 16 + lr) * 32 + kq];
        #pragma unroll
        for (int j = 0; j < 4; ++j)
            bf[j] = *(const short8*)&Bs[cur * 4096 + (nq + j * 16 + lr) * 32 + kq];
        #pragma unroll
        for (int i = 0; i < 4; ++i)
            #pragma unroll
            for (int j = 0; j < 4; ++j)
                acc[i][j] = __builtin_amdgcn_mfma_f32_16x16x32_bf16(af[i], bf[j], acc[i][j], 0, 0, 0);
    }

    const int rr = (L >> 4) * 4;
    #pragma unroll
    for (int i = 0; i < 4; ++i) {
        #pragma unroll
        for (int r = 0; r < 4; ++r) {
            int m = m0 + mq + i * 16 + rr + r;
            if (m < M) {
                #pragma unroll
                for (int j = 0; j < 4; ++j) {
                    int n = n0 + nq + j * 16 + lr;
                    C[(size_t)m * 256 + n] = acc[i][j][r] + bias[n];
                }
            }
        }
    }
}

// ---------------------------------------------------------------------------
// Sampler v10 (unchanged): full-line gathers via pair-duplicated head-major
// vdup table; head-partitioned for XCD-L2 residency.
// ---------------------------------------------------------------------------
__global__ __launch_bounds__(256) void sample10(
    const unsigned short* __restrict__ vdup,   // bf16 [16][LEN_IN+1][64]
    const unsigned short* __restrict__ off,    // bf16 [MTOT,256]
    const unsigned short* __restrict__ attn,   // bf16 [MTOT,128]
    const float* __restrict__ refpts,          // [LEN_Q, LEVELS, 2]
    const int*   __restrict__ spatial,         // [LEVELS,2] (H,W)
    const int*   __restrict__ lsi,             // [LEVELS]
    unsigned short* __restrict__ samp)         // bf16 [MTOT,256]
{
    const int b = blockIdx.x;
    const int h = b & 7;            // head -> XCD (round-robin)
    const int chunk = b >> 3;       // 0..830
    const int t = threadIdx.x;
    const int rl = t >> 3;          // local row 0..31
    const int j = t & 7;            // lane within row

    int row = chunk * 32 + rl;
    const bool valid = row < MTOT;
    if (row > MTOT - 1) row = MTOT - 1;
    const int frame = row >= LEN_Q ? 1 : 0;
    const int q = row - frame * LEN_Q;

    __shared__ float w_s[32][68];   // 4 slot-weights per lp (padded stride)
    __shared__ int   b_s[32][20];   // pair-base byte offset per lp

    uint2v ov = *(const uint2v*)(off + (size_t)row * 256 + h * 32 + j * 4);
    unsigned av = *(const unsigned*)(attn + (size_t)row * 128 + h * 16 + j * 2);
    float t0 = bf2f((unsigned short)(av & 0xffffu));
    float t1 = bf2f((unsigned short)(av >> 16));

    float m = fmaxf(t0, t1);
    #pragma unroll
    for (int d = 1; d < 8; d <<= 1) m = fmaxf(m, __shfl_xor(m, d));
    float e0 = __expf(t0 - m);
    float e1 = __expf(t1 - m);
    float s = e0 + e1;
    #pragma unroll
    for (int d = 1; d < 8; d <<= 1) s += __shfl_xor(s, d);
    float inv = 1.f / s;
    float wt01[2] = { e0 * inv, e1 * inv };

    {
        const int l = j >> 1;
        const int Hl = spatial[l * 2], Wl = spatial[l * 2 + 1];
        const int start = lsi[l];
        const int slab = (frame * 8 + h) * (LEN_IN + 1);
        const float rx = refpts[((size_t)q * LEVELS + l) * 2];
        const float ry = refpts[((size_t)q * LEVELS + l) * 2 + 1];
        #pragma unroll
        for (int i = 0; i < 2; ++i) {
            const int lp = 2 * j + i;
            unsigned sel = (i == 0) ? ov.x : ov.y;
            float ox = bf2f((unsigned short)(sel & 0xffffu));
            float oy = bf2f((unsigned short)(sel >> 16));
            float locx = rx + ox * __builtin_amdgcn_rcpf((float)Wl);
            float locy = ry + oy * __builtin_amdgcn_rcpf((float)Hl);
            float wt = wt01[i];
            float x = locx * (float)Wl - 0.5f;
            float y = locy * (float)Hl - 0.5f;
            float x0f = floorf(x), y0f = floorf(y);
            float lx = x - x0f, ly = y - y0f;
            int x0 = (int)x0f, y0 = (int)y0f;
            int xbase = min(max(x0, 0), Wl - 2);
            int ybase = min(max(y0, 0), Hl - 2);
            float wxe0 = (x0 == xbase) ? (1.f - lx) : ((x0 == -1) ? lx : 0.f);
            float wxe1 = (x0 == xbase) ? lx : ((x0 == Wl - 1) ? (1.f - lx) : 0.f);
            float wye0 = (y0 == ybase) ? (1.f - ly) : ((y0 == -1) ? ly : 0.f);
            float wye1 = (y0 == ybase) ? ly : ((y0 == Hl - 1) ? (1.f - ly) : 0.f);
            b_s[rl][lp] = (slab + start + ybase * Wl + xbase) * 128;
            f32x4 wv;
            wv.x = wt * wxe0 * wye0;
            wv.y = wt * wxe1 * wye0;
            wv.z = wt * wxe0 * wye1;
            wv.w = wt * wxe1 * wye1;
            *(f32x4*)&w_s[rl][lp * 4] = wv;
        }
    }
    __syncthreads();

    const char* vb = (const char*)vdup;
    const unsigned lane16 = (unsigned)(j * 16);
    const int hi = (j >> 2) & 1;
    int ystr[4];
    #pragma unroll
    for (int l2 = 0; l2 < 4; ++l2) ystr[l2] = spatial[l2 * 2 + 1] * 128;

    f32x4  wreg[2][2];
    uint4v vbuf[2][4];
    auto fetch = [&](int buf, int g) {
        wreg[buf][0] = *(const f32x4*)&w_s[rl][(2 * g) * 4];
        wreg[buf][1] = *(const f32x4*)&w_s[rl][(2 * g + 1) * 4];
        int b0 = b_s[rl][2 * g];
        int b1 = b_s[rl][2 * g + 1];
        int ys = ystr[g >> 1];
        vbuf[buf][0] = *(const uint4v*)(vb + (unsigned)b0 + lane16);
        vbuf[buf][1] = *(const uint4v*)(vb + (unsigned)(b0 + ys) + lane16);
        vbuf[buf][2] = *(const uint4v*)(vb + (unsigned)b1 + lane16);
        vbuf[buf][3] = *(const uint4v*)(vb + (unsigned)(b1 + ys) + lane16);
    };

    float a[8];
    #pragma unroll
    for (int k = 0; k < 8; ++k) a[k] = 0.f;

    fetch(0, 0);
    #pragma unroll
    for (int g = 0; g < 8; ++g) {
        const int cur = g & 1;
        if (g < 7) fetch(cur ^ 1, g + 1);
        #pragma unroll
        for (int p = 0; p < 2; ++p) {
            f32x4 w4 = wreg[cur][p];
            float wy0 = hi ? w4.y : w4.x;
            float wy1 = hi ? w4.w : w4.z;
            uint4v v0 = vbuf[cur][p * 2];
            uint4v v1 = vbuf[cur][p * 2 + 1];
            #pragma unroll
            for (int k = 0; k < 4; ++k) {
                unsigned u0 = v0[k], u1 = v1[k];
                a[2 * k]     = fmaf(wy0, bfl(u0), a[2 * k]);
                a[2 * k + 1] = fmaf(wy0, bfh(u0), a[2 * k + 1]);
                a[2 * k]     = fmaf(wy1, bfl(u1), a[2 * k]);
                a[2 * k + 1] = fmaf(wy1, bfh(u1), a[2 * k + 1]);
            }
        }
    }

    #pragma unroll
    for (int k = 0; k < 8; ++k) a[k] += __shfl_xor(a[k], 4);

    if (valid && hi == 0) {
        uint4v o;
        #pragma unroll
        for (int k = 0; k < 4; ++k)
            o[k] = (unsigned)f2bf(a[2 * k]) | ((unsigned)f2bf(a[2 * k + 1]) << 16);
        *(uint4v*)(samp + (size_t)row * 256 + h * 32 + (j & 3) * 8) = o;
    }
}

// ---------------------------------------------------------------------------
extern "C" void kernel_launch(void* const* d_in, const int* in_sizes, int n_in,
                              void* d_out, int out_size, void* d_ws, size_t ws_size,
                              hipStream_t stream)
{
    const float* query   = (const float*)d_in[0];
    const float* refpts  = (const float*)d_in[1];
    const float* inflat  = (const float*)d_in[2];
    const int*   spatial = (const int*)d_in[3];
    const int*   lsi     = (const int*)d_in[4];
    const float* Wv      = (const float*)d_in[5];
    const float* bv      = (const float*)d_in[6];
    const float* Woff    = (const float*)d_in[7];
    const float* boff    = (const float*)d_in[8];
    const float* Wattn   = (const float*)d_in[9];
    const float* battn   = (const float*)d_in[10];
    const float* Wout    = (const float*)d_in[11];
    const float* bout    = (const float*)d_in[12];

    unsigned short* ws = (unsigned short*)d_ws;
    const size_t MR = (size_t)MTOT * 256;                // 6,806,528 shorts
    const size_t VDUP = (size_t)16 * (LEN_IN + 1) * 64;  // 13,614,080 shorts
    unsigned short* vdup   = ws;
    unsigned short* off16  = vdup + VDUP;                // MTOT*256
    unsigned short* at16   = off16 + MR;                 // MTOT*128
    unsigned short* samp16 = at16 + (size_t)MTOT * 128;  // MTOT*256
    unsigned short* a16v   = samp16 + MR;                // MTOT*256 (bf16 inflat)
    unsigned short* a16q   = a16v + MR;                  // MTOT*256 (bf16 query)
    unsigned short* wvT    = a16q + MR;                  // 256*256
    unsigned short* woaT   = wvT + 65536;                // 384*256
    unsigned short* woutT  = woaT + 98304;               // 256*256

    dim3 blk256(256);

    hipLaunchKernelGGL(prep_all, dim3(896 + CONV_BLOCKS), blk256, 0, stream,
                       Wv, Woff, Wattn, Wout, wvT, woaT, woutT,
                       inflat, query, a16v, a16q);

    // 1040 = 8 xcd * 26 m-groups * 5 nt (XCD co-location swizzle)
    hipLaunchKernelGGL(gemm_fused3, dim3(1040), blk256, 0, stream,
                       a16v, a16q, wvT, woaT, bv, boff, battn,
                       vdup, off16, at16, MTOT);

    // 831 chunks of 32 rows per head, 8 heads -> 6648 blocks
    hipLaunchKernelGGL(sample10, dim3(6648), blk256, 0, stream,
                       vdup, off16, at16, refpts, spatial, lsi, samp16);

    // 416 = 8 xcd * 26 m-groups * 2 nt
    hipLaunchKernelGGL(gemm_out3, dim3(416), blk256, 0, stream,
                       samp16, woutT, bout, (float*)d_out, MTOT);
}

// Round 8
// 185.683 us; speedup vs baseline: 1.3914x; 1.1265x over previous
//
#include <hip/hip_runtime.h>
#include <math.h>

#define LEN_Q 13294
#define LEN_IN 13294
#define NFRAMES 2
#define MTOT (LEN_Q * NFRAMES)   // 26588
#define HEADS 8
#define LEVELS 4
#define POINTS 4

typedef __attribute__((ext_vector_type(8))) short short8;
typedef __attribute__((ext_vector_type(4))) float f32x4;
typedef __attribute__((ext_vector_type(2))) unsigned int uint2v;
typedef __attribute__((ext_vector_type(4))) unsigned int uint4v;

__device__ __forceinline__ unsigned short f2bf(float x) {
    unsigned u = __builtin_bit_cast(unsigned, x);
    unsigned r = (u + 0x7fffu + ((u >> 16) & 1u)) >> 16;
    return (unsigned short)r;
}
__device__ __forceinline__ float bf2f(unsigned short b) {
    return __builtin_bit_cast(float, (unsigned)b << 16);
}
__device__ __forceinline__ float bfl(unsigned u) {
    return __builtin_bit_cast(float, u << 16);
}
__device__ __forceinline__ float bfh(unsigned u) {
    return __builtin_bit_cast(float, u & 0xffff0000u);
}
__device__ __forceinline__ short8 pack8(f32x4 x0, f32x4 x1) {
    short8 p;
    p[0]=(short)f2bf(x0.x); p[1]=(short)f2bf(x0.y); p[2]=(short)f2bf(x0.z); p[3]=(short)f2bf(x0.w);
    p[4]=(short)f2bf(x1.x); p[5]=(short)f2bf(x1.y); p[6]=(short)f2bf(x1.z); p[7]=(short)f2bf(x1.w);
    return p;
}

// async global->LDS, 16B per lane. LDS dest must be wave-uniform base + lane*16.
__device__ __forceinline__ void gld_lds16(const unsigned short* g, unsigned short* l) {
    __builtin_amdgcn_global_load_lds(
        (const __attribute__((address_space(1))) void*)g,
        (__attribute__((address_space(3))) void*)l, 16, 0, 0);
}

// Stage a 128-row x 32-short tile (row stride 256 shorts in global) into linear
// LDS [128][32]. 256 threads x 2 loads.
__device__ __forceinline__ void stage_tile(const unsigned short* __restrict__ g,
                                           unsigned short* lds, int t) {
    const unsigned short* ga = g + (t >> 2) * 256 + (t & 3) * 8;
    gld_lds16(ga, lds + t * 8);
    gld_lds16(ga + 64 * 256, lds + 2048 + t * 8);
}

// ---------------------------------------------------------------------------
// prep_all: weight transposes (blocks 0..895) + f32->bf16 conversion of both
// A matrices (blocks 896.., grid-stride) in ONE dispatch.
// ---------------------------------------------------------------------------
#define CONV_BLOCKS 2048
__global__ __launch_bounds__(256) void prep_all(
    const float* __restrict__ Wv,  const float* __restrict__ Woff,
    const float* __restrict__ Wat, const float* __restrict__ Wout,
    unsigned short* __restrict__ wvT,   // 256x256
    unsigned short* __restrict__ woaT,  // 384x256
    unsigned short* __restrict__ woutT, // 256x256
    const float* __restrict__ a, const float* __restrict__ b,
    unsigned short* __restrict__ oa, unsigned short* __restrict__ ob)
{
    const int blk = blockIdx.x;
    const int k = threadIdx.x;
    if (blk < 896) {
        const float* src; unsigned short* dst; int N; int n;
        if (blk < 256)      { src = Wv;   dst = wvT;          N = 256; n = blk; }
        else if (blk < 512) { src = Woff; dst = woaT;         N = 256; n = blk - 256; }
        else if (blk < 640) { src = Wat;  dst = woaT + 65536; N = 128; n = blk - 512; }
        else                { src = Wout; dst = woutT;        N = 256; n = blk - 640; }
        dst[(size_t)n * 256 + k] = f2bf(src[(size_t)k * N + n]);
        return;
    }
    size_t gid = (size_t)(blk - 896) * 256 + k;
    size_t stride = (size_t)CONV_BLOCKS * 256;
    const size_t n8 = (size_t)MTOT * 256 / 8;
    for (size_t i = gid; i < n8; i += stride) {
        size_t off = i * 8;
        f32x4 x0 = *(const f32x4*)(a + off);
        f32x4 x1 = *(const f32x4*)(a + off + 4);
        *(short8*)(oa + off) = pack8(x0, x1);
        f32x4 y0 = *(const f32x4*)(b + off);
        f32x4 y1 = *(const f32x4*)(b + off + 4);
        *(short8*)(ob + off) = pack8(y0, y1);
    }
}

// ---------------------------------------------------------------------------
// gemm_fused4: m97-style K-loop (unchanged from R7) + LDS-staged epilogue:
// the 128x128 bf16 C-tile (bias added, identical f2bf) is staged into LDS
// (reusing the staging buffers, stride 136 shorts) and copied out in 16B
// fully-coalesced chunks. Replaces ~96 scattered 2-byte stores/thread with
// ~16 16-byte stores/thread (vdup chunks read once, stored to lo+hi slots).
// ---------------------------------------------------------------------------
#define CSTR 136   // C-tile LDS row stride (shorts); 272B = 17*16 -> aligned
__global__ __launch_bounds__(256) void gemm_fused4(
    const unsigned short* __restrict__ A16v,  // bf16 [MTOT,256]
    const unsigned short* __restrict__ A16q,  // bf16 [MTOT,256]
    const unsigned short* __restrict__ BTv,   // [256,256]
    const unsigned short* __restrict__ BToa,  // [384,256]
    const float* __restrict__ bv,
    const float* __restrict__ boff,
    const float* __restrict__ battn,
    unsigned short* __restrict__ vdup,
    unsigned short* __restrict__ off16,
    unsigned short* __restrict__ at16,
    int M)
{
    __shared__ __align__(16) unsigned char shraw[128 * CSTR * 2];  // 34816 B
    unsigned short* As = (unsigned short*)shraw;            // 2 x 4096 shorts
    unsigned short* Bs = (unsigned short*)(shraw + 16384);  // 2 x 4096 shorts
    unsigned short* Cs = (unsigned short*)shraw;            // 128 x CSTR

    const int t = threadIdx.x;
    const int w = t >> 6;
    const int L = t & 63;

    const int bid = blockIdx.x;
    const int xcd = bid & 7;
    const int kk = bid >> 3;                  // 0..129
    const int nt = kk % 5;
    const int m0 = ((kk / 5) * 8 + xcd) * 128;

    const unsigned short* Abase = ((nt < 2) ? A16v : A16q) + (size_t)m0 * 256;
    const unsigned short* Bbase = (nt < 2) ? (BTv + (size_t)nt * 128 * 256)
                                           : (BToa + (size_t)(nt - 2) * 128 * 256);

    const int mq = (w & 1) * 64;
    const int nq = (w >> 1) * 64;
    const int lr = L & 15;
    const int kq = (L >> 4) * 8;

    f32x4 acc[4][4];
    #pragma unroll
    for (int i = 0; i < 4; ++i)
        #pragma unroll
        for (int j = 0; j < 4; ++j) acc[i][j] = (f32x4){0.f, 0.f, 0.f, 0.f};

    stage_tile(Abase, As, t);
    stage_tile(Bbase, Bs, t);

    #pragma unroll
    for (int ks = 0; ks < 8; ++ks) {
        const int cur = ks & 1;
        __syncthreads();                       // drains vmcnt -> buf[cur] ready
        if (ks < 7) {                          // prefetch next k-tile
            stage_tile(Abase + (ks + 1) * 32, As + (cur ^ 1) * 4096, t);
            stage_tile(Bbase + (ks + 1) * 32, Bs + (cur ^ 1) * 4096, t);
        }
        short8 af[4], bf[4];
        #pragma unroll
        for (int i = 0; i < 4; ++i)
            af[i] = *(const short8*)&As[cur * 4096 + (mq + i * 16 + lr) * 32 + kq];
        #pragma unroll
        for (int j = 0; j < 4; ++j)
            bf[j] = *(const short8*)&Bs[cur * 4096 + (nq + j * 16 + lr) * 32 + kq];
        #pragma unroll
        for (int i = 0; i < 4; ++i)
            #pragma unroll
            for (int j = 0; j < 4; ++j)
                acc[i][j] = __builtin_amdgcn_mfma_f32_16x16x32_bf16(af[i], bf[j], acc[i][j], 0, 0, 0);
    }

    __syncthreads();                           // all LDS reads done -> reuse as Cs

    // ---- stage C tile (bias added, same f2bf as before) into LDS ----
    const int rr = (L >> 4) * 4;
    {
        float bj[4];
        #pragma unroll
        for (int j = 0; j < 4; ++j) {
            int colg = nt * 128 + nq + j * 16 + lr;
            bj[j] = (colg < 256) ? bv[colg]
                  : (colg < 512) ? boff[colg - 256] : battn[colg - 512];
        }
        #pragma unroll
        for (int i = 0; i < 4; ++i)
            #pragma unroll
            for (int r = 0; r < 4; ++r) {
                int mloc = mq + i * 16 + rr + r;
                #pragma unroll
                for (int j = 0; j < 4; ++j)
                    Cs[mloc * CSTR + nq + j * 16 + lr] = f2bf(acc[i][j][r] + bj[j]);
            }
    }
    __syncthreads();

    // ---- wide coalesced copy-out (16B chunks) ----
    if (nt < 2) {
        // vdup: per row, 4 heads x 4 chunks of 16B; each chunk stored to the
        // lo slot of entry e and (if e>0) the hi slot of entry e-1.
        #pragma unroll
        for (int it = 0; it < 8; ++it) {
            int idx = it * 256 + t;            // 0..2047 = 128 rows x 16
            int row = idx >> 4;
            int rem = idx & 15;
            int hh_loc = rem >> 2;
            int cc = rem & 3;
            int m = m0 + row;
            if (m < M) {
                int fr = (m >= LEN_Q) ? 1 : 0;
                int e = m - fr * LEN_Q;
                int hh = nt * 4 + hh_loc;
                uint4v v = *(const uint4v*)&Cs[row * CSTR + hh_loc * 32 + cc * 8];
                size_t eb = ((size_t)(fr * 8 + hh) * (LEN_IN + 1) + e) * 64;
                *(uint4v*)&vdup[eb + cc * 8] = v;
                if (e > 0) *(uint4v*)&vdup[eb - 64 + 32 + cc * 8] = v;
            }
        }
    } else if (nt < 4) {
        #pragma unroll
        for (int it = 0; it < 8; ++it) {
            int idx = it * 256 + t;
            int row = idx >> 4;
            int c16 = idx & 15;
            int m = m0 + row;
            if (m < M) {
                uint4v v = *(const uint4v*)&Cs[row * CSTR + c16 * 8];
                *(uint4v*)&off16[(size_t)m * 256 + (nt - 2) * 128 + c16 * 8] = v;
            }
        }
    } else {
        #pragma unroll
        for (int it = 0; it < 8; ++it) {
            int idx = it * 256 + t;
            int row = idx >> 4;
            int c16 = idx & 15;
            int m = m0 + row;
            if (m < M) {
                uint4v v = *(const uint4v*)&Cs[row * CSTR + c16 * 8];
                *(uint4v*)&at16[(size_t)m * 128 + c16 * 8] = v;
            }
        }
    }
}

// ---------------------------------------------------------------------------
// gemm_out3: unchanged from R7 (XCD-swizzled, gld_lds staging).
// ---------------------------------------------------------------------------
__global__ __launch_bounds__(256) void gemm_out3(
    const unsigned short* __restrict__ A,     // bf16 [MTOT,256]
    const unsigned short* __restrict__ BT,    // [256,256]
    const float* __restrict__ bias,
    float* __restrict__ C,
    int M)
{
    __shared__ unsigned short As[2 * 4096];
    __shared__ unsigned short Bs[2 * 4096];

    const int t = threadIdx.x;
    const int w = t >> 6;
    const int L = t & 63;

    const int bid = blockIdx.x;
    const int xcd = bid & 7;
    const int kk = bid >> 3;                  // 0..51
    const int nt = kk % 2;
    const int m0 = ((kk / 2) * 8 + xcd) * 128;
    const int n0 = nt * 128;

    const unsigned short* Abase = A + (size_t)m0 * 256;
    const unsigned short* Bbase = BT + (size_t)n0 * 256;

    const int mq = (w & 1) * 64;
    const int nq = (w >> 1) * 64;
    const int lr = L & 15;
    const int kq = (L >> 4) * 8;

    f32x4 acc[4][4];
    #pragma unroll
    for (int i = 0; i < 4; ++i)
        #pragma unroll
        for (int j = 0; j < 4; ++j) acc[i][j] = (f32x4){0.f, 0.f, 0.f, 0.f};

    stage_tile(Abase, As, t);
    stage_tile(Bbase, Bs, t);

    #pragma unroll
    for (int ks = 0; ks < 8; ++ks) {
        const int cur = ks & 1;
        __syncthreads();
        if (ks < 7) {
            stage_tile(Abase + (ks + 1) * 32, As + (cur ^ 1) * 4096, t);
            stage_tile(Bbase + (ks + 1) * 32, Bs + (cur ^ 1) * 4096, t);
        }
        short8 af[4], bf[4];
        #pragma unroll
        for (int i = 0; i < 4; ++i)
            af[i] = *(const short8*)&As[cur * 4096 + (mq + i * 16 + lr) * 32 + kq];
        #pragma unroll
        for (int j = 0; j < 4; ++j)
            bf[j] = *(const short8*)&Bs[cur * 4096 + (nq + j * 16 + lr) * 32 + kq];
        #pragma unroll
        for (int i = 0; i < 4; ++i)
            #pragma unroll
            for (int j = 0; j < 4; ++j)
                acc[i][j] = __builtin_amdgcn_mfma_f32_16x16x32_bf16(af[i], bf[j], acc[i][j], 0, 0, 0);
    }

    const int rr = (L >> 4) * 4;
    #pragma unroll
    for (int i = 0; i < 4; ++i) {
        #pragma unroll
        for (int r = 0; r < 4; ++r) {
            int m = m0 + mq + i * 16 + rr + r;
            if (m < M) {
                #pragma unroll
                for (int j = 0; j < 4; ++j) {
                    int n = n0 + nq + j * 16 + lr;
                    C[(size_t)m * 256 + n] = acc[i][j][r] + bias[n];
                }
            }
        }
    }
}

// ---------------------------------------------------------------------------
// Sampler v10 (unchanged): full-line gathers via pair-duplicated head-major
// vdup table; head-partitioned for XCD-L2 residency.
// ---------------------------------------------------------------------------
__global__ __launch_bounds__(256) void sample10(
    const unsigned short* __restrict__ vdup,   // bf16 [16][LEN_IN+1][64]
    const unsigned short* __restrict__ off,    // bf16 [MTOT,256]
    const unsigned short* __restrict__ attn,   // bf16 [MTOT,128]
    const float* __restrict__ refpts,          // [LEN_Q, LEVELS, 2]
    const int*   __restrict__ spatial,         // [LEVELS,2] (H,W)
    const int*   __restrict__ lsi,             // [LEVELS]
    unsigned short* __restrict__ samp)         // bf16 [MTOT,256]
{
    const int b = blockIdx.x;
    const int h = b & 7;            // head -> XCD (round-robin)
    const int chunk = b >> 3;       // 0..830
    const int t = threadIdx.x;
    const int rl = t >> 3;          // local row 0..31
    const int j = t & 7;            // lane within row

    int row = chunk * 32 + rl;
    const bool valid = row < MTOT;
    if (row > MTOT - 1) row = MTOT - 1;
    const int frame = row >= LEN_Q ? 1 : 0;
    const int q = row - frame * LEN_Q;

    __shared__ float w_s[32][68];   // 4 slot-weights per lp (padded stride)
    __shared__ int   b_s[32][20];   // pair-base byte offset per lp

    uint2v ov = *(const uint2v*)(off + (size_t)row * 256 + h * 32 + j * 4);
    unsigned av = *(const unsigned*)(attn + (size_t)row * 128 + h * 16 + j * 2);
    float t0 = bf2f((unsigned short)(av & 0xffffu));
    float t1 = bf2f((unsigned short)(av >> 16));

    float m = fmaxf(t0, t1);
    #pragma unroll
    for (int d = 1; d < 8; d <<= 1) m = fmaxf(m, __shfl_xor(m, d));
    float e0 = __expf(t0 - m);
    float e1 = __expf(t1 - m);
    float s = e0 + e1;
    #pragma unroll
    for (int d = 1; d < 8; d <<= 1) s += __shfl_xor(s, d);
    float inv = 1.f / s;
    float wt01[2] = { e0 * inv, e1 * inv };

    {
        const int l = j >> 1;
        const int Hl = spatial[l * 2], Wl = spatial[l * 2 + 1];
        const int start = lsi[l];
        const int slab = (frame * 8 + h) * (LEN_IN + 1);
        const float rx = refpts[((size_t)q * LEVELS + l) * 2];
        const float ry = refpts[((size_t)q * LEVELS + l) * 2 + 1];
        #pragma unroll
        for (int i = 0; i < 2; ++i) {
            const int lp = 2 * j + i;
            unsigned sel = (i == 0) ? ov.x : ov.y;
            float ox = bf2f((unsigned short)(sel & 0xffffu));
            float oy = bf2f((unsigned short)(sel >> 16));
            float locx = rx + ox * __builtin_amdgcn_rcpf((float)Wl);
            float locy = ry + oy * __builtin_amdgcn_rcpf((float)Hl);
            float wt = wt01[i];
            float x = locx * (float)Wl - 0.5f;
            float y = locy * (float)Hl - 0.5f;
            float x0f = floorf(x), y0f = floorf(y);
            float lx = x - x0f, ly = y - y0f;
            int x0 = (int)x0f, y0 = (int)y0f;
            int xbase = min(max(x0, 0), Wl - 2);
            int ybase = min(max(y0, 0), Hl - 2);
            float wxe0 = (x0 == xbase) ? (1.f - lx) : ((x0 == -1) ? lx : 0.f);
            float wxe1 = (x0 == xbase) ? lx : ((x0 == Wl - 1) ? (1.f - lx) : 0.f);
            float wye0 = (y0 == ybase) ? (1.f - ly) : ((y0 == -1) ? ly : 0.f);
            float wye1 = (y0 == ybase) ? ly : ((y0 == Hl - 1) ? (1.f - ly) : 0.f);
            b_s[rl][lp] = (slab + start + ybase * Wl + xbase) * 128;
            f32x4 wv;
            wv.x = wt * wxe0 * wye0;
            wv.y = wt * wxe1 * wye0;
            wv.z = wt * wxe0 * wye1;
            wv.w = wt * wxe1 * wye1;
            *(f32x4*)&w_s[rl][lp * 4] = wv;
        }
    }
    __syncthreads();

    const char* vb = (const char*)vdup;
    const unsigned lane16 = (unsigned)(j * 16);
    const int hi = (j >> 2) & 1;
    int ystr[4];
    #pragma unroll
    for (int l2 = 0; l2 < 4; ++l2) ystr[l2] = spatial[l2 * 2 + 1] * 128;

    f32x4  wreg[2][2];
    uint4v vbuf[2][4];
    auto fetch = [&](int buf, int g) {
        wreg[buf][0] = *(const f32x4*)&w_s[rl][(2 * g) * 4];
        wreg[buf][1] = *(const f32x4*)&w_s[rl][(2 * g + 1) * 4];
        int b0 = b_s[rl][2 * g];
        int b1 = b_s[rl][2 * g + 1];
        int ys = ystr[g >> 1];
        vbuf[buf][0] = *(const uint4v*)(vb + (unsigned)b0 + lane16);
        vbuf[buf][1] = *(const uint4v*)(vb + (unsigned)(b0 + ys) + lane16);
        vbuf[buf][2] = *(const uint4v*)(vb + (unsigned)b1 + lane16);
        vbuf[buf][3] = *(const uint4v*)(vb + (unsigned)(b1 + ys) + lane16);
    };

    float a[8];
    #pragma unroll
    for (int k = 0; k < 8; ++k) a[k] = 0.f;

    fetch(0, 0);
    #pragma unroll
    for (int g = 0; g < 8; ++g) {
        const int cur = g & 1;
        if (g < 7) fetch(cur ^ 1, g + 1);
        #pragma unroll
        for (int p = 0; p < 2; ++p) {
            f32x4 w4 = wreg[cur][p];
            float wy0 = hi ? w4.y : w4.x;
            float wy1 = hi ? w4.w : w4.z;
            uint4v v0 = vbuf[cur][p * 2];
            uint4v v1 = vbuf[cur][p * 2 + 1];
            #pragma unroll
            for (int k = 0; k < 4; ++k) {
                unsigned u0 = v0[k], u1 = v1[k];
                a[2 * k]     = fmaf(wy0, bfl(u0), a[2 * k]);
                a[2 * k + 1] = fmaf(wy0, bfh(u0), a[2 * k + 1]);
                a[2 * k]     = fmaf(wy1, bfl(u1), a[2 * k]);
                a[2 * k + 1] = fmaf(wy1, bfh(u1), a[2 * k + 1]);
            }
        }
    }

    #pragma unroll
    for (int k = 0; k < 8; ++k) a[k] += __shfl_xor(a[k], 4);

    if (valid && hi == 0) {
        uint4v o;
        #pragma unroll
        for (int k = 0; k < 4; ++k)
            o[k] = (unsigned)f2bf(a[2 * k]) | ((unsigned)f2bf(a[2 * k + 1]) << 16);
        *(uint4v*)(samp + (size_t)row * 256 + h * 32 + (j & 3) * 8) = o;
    }
}

// ---------------------------------------------------------------------------
extern "C" void kernel_launch(void* const* d_in, const int* in_sizes, int n_in,
                              void* d_out, int out_size, void* d_ws, size_t ws_size,
                              hipStream_t stream)
{
    const float* query   = (const float*)d_in[0];
    const float* refpts  = (const float*)d_in[1];
    const float* inflat  = (const float*)d_in[2];
    const int*   spatial = (const int*)d_in[3];
    const int*   lsi     = (const int*)d_in[4];
    const float* Wv      = (const float*)d_in[5];
    const float* bv      = (const float*)d_in[6];
    const float* Woff    = (const float*)d_in[7];
    const float* boff    = (const float*)d_in[8];
    const float* Wattn   = (const float*)d_in[9];
    const float* battn   = (const float*)d_in[10];
    const float* Wout    = (const float*)d_in[11];
    const float* bout    = (const float*)d_in[12];

    unsigned short* ws = (unsigned short*)d_ws;
    const size_t MR = (size_t)MTOT * 256;                // 6,806,528 shorts
    const size_t VDUP = (size_t)16 * (LEN_IN + 1) * 64;  // 13,614,080 shorts
    unsigned short* vdup   = ws;
    unsigned short* off16  = vdup + VDUP;                // MTOT*256
    unsigned short* at16   = off16 + MR;                 // MTOT*128
    unsigned short* samp16 = at16 + (size_t)MTOT * 128;  // MTOT*256
    unsigned short* a16v   = samp16 + MR;                // MTOT*256 (bf16 inflat)
    unsigned short* a16q   = a16v + MR;                  // MTOT*256 (bf16 query)
    unsigned short* wvT    = a16q + MR;                  // 256*256
    unsigned short* woaT   = wvT + 65536;                // 384*256
    unsigned short* woutT  = woaT + 98304;               // 256*256

    dim3 blk256(256);

    hipLaunchKernelGGL(prep_all, dim3(896 + CONV_BLOCKS), blk256, 0, stream,
                       Wv, Woff, Wattn, Wout, wvT, woaT, woutT,
                       inflat, query, a16v, a16q);

    // 1040 = 8 xcd * 26 m-groups * 5 nt (XCD co-location swizzle)
    hipLaunchKernelGGL(gemm_fused4, dim3(1040), blk256, 0, stream,
                       a16v, a16q, wvT, woaT, bv, boff, battn,
                       vdup, off16, at16, MTOT);

    // 831 chunks of 32 rows per head, 8 heads -> 6648 blocks
    hipLaunchKernelGGL(sample10, dim3(6648), blk256, 0, stream,
                       vdup, off16, at16, refpts, spatial, lsi, samp16);

    // 416 = 8 xcd * 26 m-groups * 2 nt
    hipLaunchKernelGGL(gemm_out3, dim3(416), blk256, 0, stream,
                       samp16, woutT, bout, (float*)d_out, MTOT);
}

// Round 10
// 183.605 us; speedup vs baseline: 1.4072x; 1.0113x over previous
//
#include <hip/hip_runtime.h>
#include <math.h>

#define LEN_Q 13294
#define LEN_IN 13294
#define NFRAMES 2
#define MTOT (LEN_Q * NFRAMES)   // 26588
#define HEADS 8
#define LEVELS 4
#define POINTS 4

typedef __attribute__((ext_vector_type(8))) short short8;
typedef __attribute__((ext_vector_type(4))) float f32x4;
typedef __attribute__((ext_vector_type(2))) float f32x2;
typedef __attribute__((ext_vector_type(2))) unsigned int uint2v;
typedef __attribute__((ext_vector_type(4))) unsigned int uint4v;

__device__ __forceinline__ unsigned short f2bf(float x) {
    unsigned u = __builtin_bit_cast(unsigned, x);
    unsigned r = (u + 0x7fffu + ((u >> 16) & 1u)) >> 16;
    return (unsigned short)r;
}
__device__ __forceinline__ float bf2f(unsigned short b) {
    return __builtin_bit_cast(float, (unsigned)b << 16);
}
__device__ __forceinline__ float bfl(unsigned u) {
    return __builtin_bit_cast(float, u << 16);
}
__device__ __forceinline__ float bfh(unsigned u) {
    return __builtin_bit_cast(float, u & 0xffff0000u);
}
__device__ __forceinline__ short8 pack8(f32x4 x0, f32x4 x1) {
    short8 p;
    p[0]=(short)f2bf(x0.x); p[1]=(short)f2bf(x0.y); p[2]=(short)f2bf(x0.z); p[3]=(short)f2bf(x0.w);
    p[4]=(short)f2bf(x1.x); p[5]=(short)f2bf(x1.y); p[6]=(short)f2bf(x1.z); p[7]=(short)f2bf(x1.w);
    return p;
}

// async global->LDS, 16B per lane. LDS dest must be wave-uniform base + lane*16.
__device__ __forceinline__ void gld_lds16(const unsigned short* g, unsigned short* l) {
    __builtin_amdgcn_global_load_lds(
        (const __attribute__((address_space(1))) void*)g,
        (__attribute__((address_space(3))) void*)l, 16, 0, 0);
}

// Stage a 128-row x 32-short tile (row stride 256 shorts in global) into linear
// LDS [128][32]. 256 threads x 2 loads.
__device__ __forceinline__ void stage_tile(const unsigned short* __restrict__ g,
                                           unsigned short* lds, int t) {
    const unsigned short* ga = g + (t >> 2) * 256 + (t & 3) * 8;
    gld_lds16(ga, lds + t * 8);
    gld_lds16(ga + 64 * 256, lds + 2048 + t * 8);
}

// ---------------------------------------------------------------------------
// prep_all: weight transposes (blocks 0..895) + f32->bf16 conversion of both
// A matrices (blocks 896.., grid-stride) in ONE dispatch.
// ---------------------------------------------------------------------------
#define CONV_BLOCKS 2048
__global__ __launch_bounds__(256) void prep_all(
    const float* __restrict__ Wv,  const float* __restrict__ Woff,
    const float* __restrict__ Wat, const float* __restrict__ Wout,
    unsigned short* __restrict__ wvT,   // 256x256
    unsigned short* __restrict__ woaT,  // 384x256
    unsigned short* __restrict__ woutT, // 256x256
    const float* __restrict__ a, const float* __restrict__ b,
    unsigned short* __restrict__ oa, unsigned short* __restrict__ ob)
{
    const int blk = blockIdx.x;
    const int k = threadIdx.x;
    if (blk < 896) {
        const float* src; unsigned short* dst; int N; int n;
        if (blk < 256)      { src = Wv;   dst = wvT;          N = 256; n = blk; }
        else if (blk < 512) { src = Woff; dst = woaT;         N = 256; n = blk - 256; }
        else if (blk < 640) { src = Wat;  dst = woaT + 65536; N = 128; n = blk - 512; }
        else                { src = Wout; dst = woutT;        N = 256; n = blk - 640; }
        dst[(size_t)n * 256 + k] = f2bf(src[(size_t)k * N + n]);
        return;
    }
    size_t gid = (size_t)(blk - 896) * 256 + k;
    size_t stride = (size_t)CONV_BLOCKS * 256;
    const size_t n8 = (size_t)MTOT * 256 / 8;
    for (size_t i = gid; i < n8; i += stride) {
        size_t off = i * 8;
        f32x4 x0 = *(const f32x4*)(a + off);
        f32x4 x1 = *(const f32x4*)(a + off + 4);
        *(short8*)(oa + off) = pack8(x0, x1);
        f32x4 y0 = *(const f32x4*)(b + off);
        f32x4 y1 = *(const f32x4*)(b + off + 4);
        *(short8*)(ob + off) = pack8(y0, y1);
    }
}

// ---------------------------------------------------------------------------
// gemm_fused4 (unchanged from R8 — LDS-staged wide-store epilogue, proven).
// ---------------------------------------------------------------------------
#define CSTR 136   // C-tile LDS row stride (shorts); 272B = 17*16 -> aligned
__global__ __launch_bounds__(256) void gemm_fused4(
    const unsigned short* __restrict__ A16v,  // bf16 [MTOT,256]
    const unsigned short* __restrict__ A16q,  // bf16 [MTOT,256]
    const unsigned short* __restrict__ BTv,   // [256,256]
    const unsigned short* __restrict__ BToa,  // [384,256]
    const float* __restrict__ bv,
    const float* __restrict__ boff,
    const float* __restrict__ battn,
    unsigned short* __restrict__ vdup,
    unsigned short* __restrict__ off16,
    unsigned short* __restrict__ at16,
    int M)
{
    __shared__ __align__(16) unsigned char shraw[128 * CSTR * 2];  // 34816 B
    unsigned short* As = (unsigned short*)shraw;            // 2 x 4096 shorts
    unsigned short* Bs = (unsigned short*)(shraw + 16384);  // 2 x 4096 shorts
    unsigned short* Cs = (unsigned short*)shraw;            // 128 x CSTR

    const int t = threadIdx.x;
    const int w = t >> 6;
    const int L = t & 63;

    const int bid = blockIdx.x;
    const int xcd = bid & 7;
    const int kk = bid >> 3;                  // 0..129
    const int nt = kk % 5;
    const int m0 = ((kk / 5) * 8 + xcd) * 128;

    const unsigned short* Abase = ((nt < 2) ? A16v : A16q) + (size_t)m0 * 256;
    const unsigned short* Bbase = (nt < 2) ? (BTv + (size_t)nt * 128 * 256)
                                           : (BToa + (size_t)(nt - 2) * 128 * 256);

    const int mq = (w & 1) * 64;
    const int nq = (w >> 1) * 64;
    const int lr = L & 15;
    const int kq = (L >> 4) * 8;

    f32x4 acc[4][4];
    #pragma unroll
    for (int i = 0; i < 4; ++i)
        #pragma unroll
        for (int j = 0; j < 4; ++j) acc[i][j] = (f32x4){0.f, 0.f, 0.f, 0.f};

    stage_tile(Abase, As, t);
    stage_tile(Bbase, Bs, t);

    #pragma unroll
    for (int ks = 0; ks < 8; ++ks) {
        const int cur = ks & 1;
        __syncthreads();                       // drains vmcnt -> buf[cur] ready
        if (ks < 7) {                          // prefetch next k-tile
            stage_tile(Abase + (ks + 1) * 32, As + (cur ^ 1) * 4096, t);
            stage_tile(Bbase + (ks + 1) * 32, Bs + (cur ^ 1) * 4096, t);
        }
        short8 af[4], bf[4];
        #pragma unroll
        for (int i = 0; i < 4; ++i)
            af[i] = *(const short8*)&As[cur * 4096 + (mq + i * 16 + lr) * 32 + kq];
        #pragma unroll
        for (int j = 0; j < 4; ++j)
            bf[j] = *(const short8*)&Bs[cur * 4096 + (nq + j * 16 + lr) * 32 + kq];
        #pragma unroll
        for (int i = 0; i < 4; ++i)
            #pragma unroll
            for (int j = 0; j < 4; ++j)
                acc[i][j] = __builtin_amdgcn_mfma_f32_16x16x32_bf16(af[i], bf[j], acc[i][j], 0, 0, 0);
    }

    __syncthreads();                           // all LDS reads done -> reuse as Cs

    const int rr = (L >> 4) * 4;
    {
        float bj[4];
        #pragma unroll
        for (int j = 0; j < 4; ++j) {
            int colg = nt * 128 + nq + j * 16 + lr;
            bj[j] = (colg < 256) ? bv[colg]
                  : (colg < 512) ? boff[colg - 256] : battn[colg - 512];
        }
        #pragma unroll
        for (int i = 0; i < 4; ++i)
            #pragma unroll
            for (int r = 0; r < 4; ++r) {
                int mloc = mq + i * 16 + rr + r;
                #pragma unroll
                for (int j = 0; j < 4; ++j)
                    Cs[mloc * CSTR + nq + j * 16 + lr] = f2bf(acc[i][j][r] + bj[j]);
            }
    }
    __syncthreads();

    if (nt < 2) {
        #pragma unroll
        for (int it = 0; it < 8; ++it) {
            int idx = it * 256 + t;            // 0..2047 = 128 rows x 16
            int row = idx >> 4;
            int rem = idx & 15;
            int hh_loc = rem >> 2;
            int cc = rem & 3;
            int m = m0 + row;
            if (m < M) {
                int fr = (m >= LEN_Q) ? 1 : 0;
                int e = m - fr * LEN_Q;
                int hh = nt * 4 + hh_loc;
                uint4v v = *(const uint4v*)&Cs[row * CSTR + hh_loc * 32 + cc * 8];
                size_t eb = ((size_t)(fr * 8 + hh) * (LEN_IN + 1) + e) * 64;
                *(uint4v*)&vdup[eb + cc * 8] = v;
                if (e > 0) *(uint4v*)&vdup[eb - 64 + 32 + cc * 8] = v;
            }
        }
    } else if (nt < 4) {
        #pragma unroll
        for (int it = 0; it < 8; ++it) {
            int idx = it * 256 + t;
            int row = idx >> 4;
            int c16 = idx & 15;
            int m = m0 + row;
            if (m < M) {
                uint4v v = *(const uint4v*)&Cs[row * CSTR + c16 * 8];
                *(uint4v*)&off16[(size_t)m * 256 + (nt - 2) * 128 + c16 * 8] = v;
            }
        }
    } else {
        #pragma unroll
        for (int it = 0; it < 8; ++it) {
            int idx = it * 256 + t;
            int row = idx >> 4;
            int c16 = idx & 15;
            int m = m0 + row;
            if (m < M) {
                uint4v v = *(const uint4v*)&Cs[row * CSTR + c16 * 8];
                *(uint4v*)&at16[(size_t)m * 128 + c16 * 8] = v;
            }
        }
    }
}

// ---------------------------------------------------------------------------
// gemm_out4: 64-row tiles (832 blocks, was 416 -> grid-starved at 1.6/CU) +
// LDS-staged f32 epilogue with 16B coalesced stores (same fix as fused4).
// ---------------------------------------------------------------------------
#define OSTR 132   // f32 C-tile LDS row stride (floats): 528B, 16-aligned
__global__ __launch_bounds__(256) void gemm_out4(
    const unsigned short* __restrict__ A,     // bf16 [MTOT,256]
    const unsigned short* __restrict__ BT,    // [256,256]
    const float* __restrict__ bias,
    float* __restrict__ C,
    int M)
{
    __shared__ __align__(16) unsigned char raw[64 * OSTR * 4];  // 33792 B
    unsigned short* As = (unsigned short*)raw;            // 2 x 2048 shorts (8KB)
    unsigned short* Bs = (unsigned short*)(raw + 8192);   // 2 x 4096 shorts (16KB)
    float* Cs = (float*)raw;                              // 64 x OSTR floats

    const int t = threadIdx.x;
    const int w = t >> 6;
    const int L = t & 63;

    const int bid = blockIdx.x;
    const int xcd = bid & 7;
    const int kk = bid >> 3;                  // 0..103
    const int nt = kk & 1;
    const int m0 = (((kk >> 1) * 8) + xcd) * 64;
    const int n0 = nt * 128;

    const unsigned short* Abase = A + (size_t)m0 * 256;
    const unsigned short* Bbase = BT + (size_t)n0 * 256;

    const int mq = (w & 1) * 32;
    const int nq = (w >> 1) * 64;
    const int lr = L & 15;
    const int kq = (L >> 4) * 8;

    f32x4 acc[2][4];
    #pragma unroll
    for (int i = 0; i < 2; ++i)
        #pragma unroll
        for (int j = 0; j < 4; ++j) acc[i][j] = (f32x4){0.f, 0.f, 0.f, 0.f};

    // A: 64x32 tile = 1 gld/thread; B: 128x32 = 2 gld/thread
    gld_lds16(Abase + (t >> 2) * 256 + (t & 3) * 8, As + t * 8);
    stage_tile(Bbase, Bs, t);

    #pragma unroll
    for (int ks = 0; ks < 8; ++ks) {
        const int cur = ks & 1;
        __syncthreads();
        if (ks < 7) {
            gld_lds16(Abase + (ks + 1) * 32 + (t >> 2) * 256 + (t & 3) * 8,
                      As + (cur ^ 1) * 2048 + t * 8);
            stage_tile(Bbase + (ks + 1) * 32, Bs + (cur ^ 1) * 4096, t);
        }
        short8 af[2], bf[4];
        #pragma unroll
        for (int i = 0; i < 2; ++i)
            af[i] = *(const short8*)&As[cur * 2048 + (mq + i * 16 + lr) * 32 + kq];
        #pragma unroll
        for (int j = 0; j < 4; ++j)
            bf[j] = *(const short8*)&Bs[cur * 4096 + (nq + j * 16 + lr) * 32 + kq];
        #pragma unroll
        for (int i = 0; i < 2; ++i)
            #pragma unroll
            for (int j = 0; j < 4; ++j)
                acc[i][j] = __builtin_amdgcn_mfma_f32_16x16x32_bf16(af[i], bf[j], acc[i][j], 0, 0, 0);
    }

    __syncthreads();                           // reuse LDS as f32 C-tile

    const int rr = (L >> 4) * 4;
    {
        float bj[4];
        #pragma unroll
        for (int j = 0; j < 4; ++j) bj[j] = bias[n0 + nq + j * 16 + lr];
        #pragma unroll
        for (int i = 0; i < 2; ++i)
            #pragma unroll
            for (int r = 0; r < 4; ++r) {
                int mloc = mq + i * 16 + rr + r;
                #pragma unroll
                for (int j = 0; j < 4; ++j)
                    Cs[mloc * OSTR + nq + j * 16 + lr] = acc[i][j][r] + bj[j];
            }
    }
    __syncthreads();

    // coalesced copy-out: 64 rows x 32 chunks of 16B
    #pragma unroll
    for (int it = 0; it < 8; ++it) {
        int idx = it * 256 + t;
        int row = idx >> 5;
        int c = idx & 31;
        int m = m0 + row;
        if (m < M) {
            f32x4 v = *(const f32x4*)&Cs[row * OSTR + c * 4];
            *(f32x4*)(C + (size_t)m * 256 + n0 + c * 4) = v;
        }
    }
}

// ---------------------------------------------------------------------------
// sample11: v10 + packed-f32 inner loop.
//   - accumulators paired as float2; __builtin_elementwise_fma -> v_pk_fma_f32
//     (bit-identical: two independent fmas per op, same chain order).
//   - w_s reordered x-corner-major: lane reads its 2 weights (y0,y1) with one
//     8B LDS read at lp*4 + hi*2 (replaces f32x4 read + 2 cndmask selects).
// ---------------------------------------------------------------------------
__global__ __launch_bounds__(256) void sample11(
    const unsigned short* __restrict__ vdup,   // bf16 [16][LEN_IN+1][64]
    const unsigned short* __restrict__ off,    // bf16 [MTOT,256]
    const unsigned short* __restrict__ attn,   // bf16 [MTOT,128]
    const float* __restrict__ refpts,          // [LEN_Q, LEVELS, 2]
    const int*   __restrict__ spatial,         // [LEVELS,2] (H,W)
    const int*   __restrict__ lsi,             // [LEVELS]
    unsigned short* __restrict__ samp)         // bf16 [MTOT,256]
{
    const int b = blockIdx.x;
    const int h = b & 7;            // head -> XCD (round-robin)
    const int chunk = b >> 3;       // 0..830
    const int t = threadIdx.x;
    const int rl = t >> 3;          // local row 0..31
    const int j = t & 7;            // lane within row

    int row = chunk * 32 + rl;
    const bool valid = row < MTOT;
    if (row > MTOT - 1) row = MTOT - 1;
    const int frame = row >= LEN_Q ? 1 : 0;
    const int q = row - frame * LEN_Q;

    __shared__ float w_s[32][68];   // 4 slot-weights per lp, x-corner-major
    __shared__ int   b_s[32][20];   // pair-base byte offset per lp

    uint2v ov = *(const uint2v*)(off + (size_t)row * 256 + h * 32 + j * 4);
    unsigned av = *(const unsigned*)(attn + (size_t)row * 128 + h * 16 + j * 2);
    float t0 = bf2f((unsigned short)(av & 0xffffu));
    float t1 = bf2f((unsigned short)(av >> 16));

    float m = fmaxf(t0, t1);
    #pragma unroll
    for (int d = 1; d < 8; d <<= 1) m = fmaxf(m, __shfl_xor(m, d));
    float e0 = __expf(t0 - m);
    float e1 = __expf(t1 - m);
    float s = e0 + e1;
    #pragma unroll
    for (int d = 1; d < 8; d <<= 1) s += __shfl_xor(s, d);
    float inv = 1.f / s;
    float wt01[2] = { e0 * inv, e1 * inv };

    {
        const int l = j >> 1;
        const int Hl = spatial[l * 2], Wl = spatial[l * 2 + 1];
        const int start = lsi[l];
        const int slab = (frame * 8 + h) * (LEN_IN + 1);
        const float rx = refpts[((size_t)q * LEVELS + l) * 2];
        const float ry = refpts[((size_t)q * LEVELS + l) * 2 + 1];
        #pragma unroll
        for (int i = 0; i < 2; ++i) {
            const int lp = 2 * j + i;
            unsigned sel = (i == 0) ? ov.x : ov.y;
            float ox = bf2f((unsigned short)(sel & 0xffffu));
            float oy = bf2f((unsigned short)(sel >> 16));
            float locx = rx + ox * __builtin_amdgcn_rcpf((float)Wl);
            float locy = ry + oy * __builtin_amdgcn_rcpf((float)Hl);
            float wt = wt01[i];
            float x = locx * (float)Wl - 0.5f;
            float y = locy * (float)Hl - 0.5f;
            float x0f = floorf(x), y0f = floorf(y);
            float lx = x - x0f, ly = y - y0f;
            int x0 = (int)x0f, y0 = (int)y0f;
            int xbase = min(max(x0, 0), Wl - 2);
            int ybase = min(max(y0, 0), Hl - 2);
            float wxe0 = (x0 == xbase) ? (1.f - lx) : ((x0 == -1) ? lx : 0.f);
            float wxe1 = (x0 == xbase) ? lx : ((x0 == Wl - 1) ? (1.f - lx) : 0.f);
            float wye0 = (y0 == ybase) ? (1.f - ly) : ((y0 == -1) ? ly : 0.f);
            float wye1 = (y0 == ybase) ? ly : ((y0 == Hl - 1) ? (1.f - ly) : 0.f);
            b_s[rl][lp] = (slab + start + ybase * Wl + xbase) * 128;
            f32x4 wv;
            wv.x = wt * wxe0 * wye0;   // e0, y0
            wv.y = wt * wxe0 * wye1;   // e0, y1
            wv.z = wt * wxe1 * wye0;   // e1, y0
            wv.w = wt * wxe1 * wye1;   // e1, y1
            *(f32x4*)&w_s[rl][lp * 4] = wv;
        }
    }
    __syncthreads();

    const char* vb = (const char*)vdup;
    const unsigned lane16 = (unsigned)(j * 16);
    const int hi2 = ((j >> 2) & 1) * 2;          // weight slot offset for my x-corner
    int ystr[4];
    #pragma unroll
    for (int l2 = 0; l2 < 4; ++l2) ystr[l2] = spatial[l2 * 2 + 1] * 128;

    f32x2  wbuf[2][2];
    uint4v vbuf[2][4];
    auto fetch = [&](int buf, int g) {
        wbuf[buf][0] = *(const f32x2*)&w_s[rl][(2 * g) * 4 + hi2];
        wbuf[buf][1] = *(const f32x2*)&w_s[rl][(2 * g + 1) * 4 + hi2];
        int b0 = b_s[rl][2 * g];
        int b1 = b_s[rl][2 * g + 1];
        int ys = ystr[g >> 1];
        vbuf[buf][0] = *(const uint4v*)(vb + (unsigned)b0 + lane16);
        vbuf[buf][1] = *(const uint4v*)(vb + (unsigned)(b0 + ys) + lane16);
        vbuf[buf][2] = *(const uint4v*)(vb + (unsigned)b1 + lane16);
        vbuf[buf][3] = *(const uint4v*)(vb + (unsigned)(b1 + ys) + lane16);
    };

    f32x2 a2[4];
    #pragma unroll
    for (int k = 0; k < 4; ++k) a2[k] = (f32x2){0.f, 0.f};

    fetch(0, 0);
    #pragma unroll
    for (int g = 0; g < 8; ++g) {
        const int cur = g & 1;
        if (g < 7) fetch(cur ^ 1, g + 1);
        #pragma unroll
        for (int p = 0; p < 2; ++p) {
            f32x2 wp = wbuf[cur][p];
            f32x2 wy0 = (f32x2){wp.x, wp.x};
            f32x2 wy1 = (f32x2){wp.y, wp.y};
            uint4v v0 = vbuf[cur][p * 2];
            uint4v v1 = vbuf[cur][p * 2 + 1];
            #pragma unroll
            for (int k = 0; k < 4; ++k) {
                f32x2 x0 = (f32x2){bfl(v0[k]), bfh(v0[k])};
                f32x2 x1 = (f32x2){bfl(v1[k]), bfh(v1[k])};
                a2[k] = __builtin_elementwise_fma(wy0, x0, a2[k]);
                a2[k] = __builtin_elementwise_fma(wy1, x1, a2[k]);
            }
        }
    }

    float a[8];
    #pragma unroll
    for (int k = 0; k < 4; ++k) { a[2 * k] = a2[k].x; a[2 * k + 1] = a2[k].y; }

    #pragma unroll
    for (int k = 0; k < 8; ++k) a[k] += __shfl_xor(a[k], 4);

    if (valid && hi2 == 0) {
        uint4v o;
        #pragma unroll
        for (int k = 0; k < 4; ++k)
            o[k] = (unsigned)f2bf(a[2 * k]) | ((unsigned)f2bf(a[2 * k + 1]) << 16);
        *(uint4v*)(samp + (size_t)row * 256 + h * 32 + (j & 3) * 8) = o;
    }
}

// ---------------------------------------------------------------------------
extern "C" void kernel_launch(void* const* d_in, const int* in_sizes, int n_in,
                              void* d_out, int out_size, void* d_ws, size_t ws_size,
                              hipStream_t stream)
{
    const float* query   = (const float*)d_in[0];
    const float* refpts  = (const float*)d_in[1];
    const float* inflat  = (const float*)d_in[2];
    const int*   spatial = (const int*)d_in[3];
    const int*   lsi     = (const int*)d_in[4];
    const float* Wv      = (const float*)d_in[5];
    const float* bv      = (const float*)d_in[6];
    const float* Woff    = (const float*)d_in[7];
    const float* boff    = (const float*)d_in[8];
    const float* Wattn   = (const float*)d_in[9];
    const float* battn   = (const float*)d_in[10];
    const float* Wout    = (const float*)d_in[11];
    const float* bout    = (const float*)d_in[12];

    unsigned short* ws = (unsigned short*)d_ws;
    const size_t MR = (size_t)MTOT * 256;                // 6,806,528 shorts
    const size_t VDUP = (size_t)16 * (LEN_IN + 1) * 64;  // 13,614,080 shorts
    unsigned short* vdup   = ws;
    unsigned short* off16  = vdup + VDUP;                // MTOT*256
    unsigned short* at16   = off16 + MR;                 // MTOT*128
    unsigned short* samp16 = at16 + (size_t)MTOT * 128;  // MTOT*256
    unsigned short* a16v   = samp16 + MR;                // MTOT*256 (bf16 inflat)
    unsigned short* a16q   = a16v + MR;                  // MTOT*256 (bf16 query)
    unsigned short* wvT    = a16q + MR;                  // 256*256
    unsigned short* woaT   = wvT + 65536;                // 384*256
    unsigned short* woutT  = woaT + 98304;               // 256*256

    dim3 blk256(256);

    hipLaunchKernelGGL(prep_all, dim3(896 + CONV_BLOCKS), blk256, 0, stream,
                       Wv, Woff, Wattn, Wout, wvT, woaT, woutT,
                       inflat, query, a16v, a16q);

    // 1040 = 8 xcd * 26 m-groups * 5 nt (XCD co-location swizzle)
    hipLaunchKernelGGL(gemm_fused4, dim3(1040), blk256, 0, stream,
                       a16v, a16q, wvT, woaT, bv, boff, battn,
                       vdup, off16, at16, MTOT);

    // 831 chunks of 32 rows per head, 8 heads -> 6648 blocks
    hipLaunchKernelGGL(sample11, dim3(6648), blk256, 0, stream,
                       vdup, off16, at16, refpts, spatial, lsi, samp16);

    // 832 = 8 xcd * 52 m-groups * 2 nt (64-row tiles)
    hipLaunchKernelGGL(gemm_out4, dim3(832), blk256, 0, stream,
                       samp16, woutT, bout, (float*)d_out, MTOT);
}